// Round 7
// baseline (6855.469 us; speedup 1.0000x reference)
//
#include <hip/hip_runtime.h>
#include <math.h>

// ---------------------------------------------------------------------------
// TransformerDecoder: weight-stationary persistent dataflow decode.
// B=8, S_SRC=256, T=64, D=256, H=8, HD=32, DFF=1024, NC=128, L=2. fp32.
// 230 blocks (1/CU, 147KB LDS each), every weight LDS-resident forever:
//   S1 [0,32):   (h,l,bhalf)  SA qkv+attn+o-proj partial
//   S2 [32,160): (b,h,l)      p1-reduce, CA (memKV in LDS), proj partial
//   S3 [160,224):(l,cg16,bh)  p2-reduce, FFN1 + FFN2 partial
//   S5a[224,228):(cg4)        r3(l1) assemble, op_w1 + BN + relu
//   S5b[228,230):(half)       logits + out write + emb partial (p5)
// Consumers assemble x_t = p5[0]+p5[1]+emb_b+pe(t,c) (sincos on the fly).
// Sync: relaxed agent-scope atomics (MALL), monotonic per-edge flags.
// ---------------------------------------------------------------------------

#define EPS_ 1e-5f
#define SCALE_ 0.17677669529663687f   // 1/sqrt(32)
#define BNS 0.99999500003749969f      // 1/sqrt(1+1e-5)
#define DEV __device__ __forceinline__
#define DYNF 36864                     // LDS floats per block (147456 B)

#define D4(a,b) ((a).x*(b).x+(a).y*(b).y+(a).z*(b).z+(a).w*(b).w)
#define F4(p)  (*(float4*)(p))
#define CF4(p) (*(const float4*)(p))

DEV float ald(const float* p){return __hip_atomic_load(p,__ATOMIC_RELAXED,__HIP_MEMORY_SCOPE_AGENT);}
DEV void  ast(float* p,float v){__hip_atomic_store(p,v,__ATOMIC_RELAXED,__HIP_MEMORY_SCOPE_AGENT);}
DEV int   aldi(const int* p){return __hip_atomic_load(p,__ATOMIC_RELAXED,__HIP_MEMORY_SCOPE_AGENT);}
DEV void  asti(int* p,int v){__hip_atomic_store(p,v,__ATOMIC_RELAXED,__HIP_MEMORY_SCOPE_AGENT);}

DEV float wsum(float v){
#pragma unroll
  for(int o=32;o;o>>=1) v+=__shfl_xor(v,o,64);
  return v;
}
DEV float wmax(float v){
#pragma unroll
  for(int o=32;o;o>>=1) v=fmaxf(v,__shfl_xor(v,o,64));
  return v;
}

// positional encoding element, computed on the fly
DEV float pev(int t,int c){
  float dv=expf((float)(c&~1)*(-9.210340371976184f/256.f)); // ln(10000)
  float a=(float)t*dv;
  return (c&1)?cosf(a):sinf(a);
}

// wait until f[0..n-1] >= s
DEV void waitge(const int* f,int n,int s){
  if((int)threadIdx.x<n){ while(aldi(f+threadIdx.x)<s){} }
  __syncthreads();
}

// In-place LayerNorm of R rows x 256 in LDS (stride 256); 256 threads.
DEV void lnR(float* x,int R,const float* __restrict__ g,const float* __restrict__ bv,float* red){
  __syncthreads();
  int tid=threadIdx.x,wid=tid>>6,lane=tid&63;
  for(int r=wid;r<R;r+=4){
    float s=0.f,s2=0.f;
    for(int i=lane;i<256;i+=64){float v=x[r*256+i];s+=v;s2+=v*v;}
    s=wsum(s);s2=wsum(s2);
    if(lane==0){float m=s*(1.f/256.f);red[r]=m;red[8+r]=rsqrtf(s2*(1.f/256.f)-m*m+EPS_);}
  }
  __syncthreads();
  for(int i=tid;i<R*256;i+=256){int r=i>>8,c=i&255;x[i]=(x[i]-red[r])*red[8+r]*g[c]+bv[c];}
  __syncthreads();
}

// ============================ S1: self-attention ============================
DEV void role_s1(float* LDS,int rid,
    const float* __restrict__ sa_wqkv,const float* __restrict__ sa_bqkv,
    const float* __restrict__ sa_wo,
    const float* __restrict__ ln2_g,const float* __restrict__ ln2_b,
    const float* __restrict__ ln3_g,const float* __restrict__ ln3_b,
    const float* __restrict__ ffn_b2,const float* __restrict__ emb_b,
    int* f1,const int* f3,const int* f5b,
    float* kc,float* vc,const float* r2red,float* r3red,
    const float* p3,float* p1,const float* p5){
  const int tid=threadIdx.x;
  const int h=rid>>2, l=(rid>>1)&1, bs=(rid&1)*4;
  float* W   =LDS;          // 96 x 260
  float* WO  =LDS+24960;    // 256 x 36
  float* XS  =LDS+34176;    // 4 x 256
  float* QKV =LDS+35200;    // 4 x 96 (q|k|v per b)
  float* SC  =LDS+35584;    // 4 x 64
  float* PART=LDS+35840;    // 4 x 64
  float* RED =LDS+36096;    // 16

  // prologue: stationary weights
  for(int idx=tid;idx<96*64;idx+=256){
    int row=idx>>6,i4=idx&63,which=row>>5,j=row&31;
    F4(&W[row*260+4*i4])=CF4(sa_wqkv+(size_t)l*196608+((size_t)(which*256+h*32+j))*256+4*i4);
  }
  for(int idx=tid;idx<256*8;idx+=256){
    int c=idx>>3,i=idx&7;
    F4(&WO[c*36+4*i])=CF4(sa_wo+(size_t)l*65536+(size_t)c*256+h*32+4*i);
  }
  __syncthreads();

  for(int t=0;t<64;++t){
    const int fv=2*t+l+1;
    const int c=tid;
    if(l==0){
      waitge(f5b,2,t);
      float peb=emb_b[c]+pev(t,c);
      for(int bi=0;bi<4;++bi){
        int b=bs+bi;
        XS[bi*256+c]=ald(p5+b*256+c)+ald(p5+2048+b*256+c)+peb;
      }
      __syncthreads();
    }else{
      waitge(f3,32,t+1);     // layer-0 S3 flags
      for(int bi=0;bi<4;++bi) XS[bi*256+c]=ald(r2red+(bs+bi)*256+c);
      lnR(XS,4,ln2_g,ln2_b,RED);            // LN2 (layer0)
      for(int bi=0;bi<4;++bi){
        int b=bs+bi;
        float s=0.f;
#pragma unroll
        for(int cg=0;cg<16;++cg) s+=ald(p3+(cg*8+b)*256+c);
        float r3v=XS[bi*256+c]+s+ffn_b2[c];
        if(h==0) ast(r3red+b*256+c,r3v);
        XS[bi*256+c]=r3v;
      }
      lnR(XS,4,ln3_g,ln3_b,RED);            // LN3 (layer0)
    }
    // qkv for current token (96 rows x 4 b, K-split 2)
    if(tid<192){
      int row=tid>>1,kq=tid&1;
      float a0=0.f,a1=0.f,a2=0.f,a3=0.f;
#pragma unroll
      for(int i=0;i<32;++i){
        float4 w=F4(&W[row*260+kq*128+4*i]);
        float4 x0=F4(&XS[0*256+kq*128+4*i]),x1=F4(&XS[1*256+kq*128+4*i]);
        float4 x2=F4(&XS[2*256+kq*128+4*i]),x3=F4(&XS[3*256+kq*128+4*i]);
        a0+=D4(w,x0);a1+=D4(w,x1);a2+=D4(w,x2);a3+=D4(w,x3);
      }
      a0+=__shfl_down(a0,1,64);a1+=__shfl_down(a1,1,64);
      a2+=__shfl_down(a2,1,64);a3+=__shfl_down(a3,1,64);
      if(kq==0){
        int which=row>>5,j=row&31;
        float bias=sa_bqkv[l*768+which*256+h*32+j];
        float v0=a0+bias,v1=a1+bias,v2=a2+bias,v3=a3+bias;
        if(which==0){
          QKV[j]=v0;QKV[96+j]=v1;QKV[192+j]=v2;QKV[288+j]=v3;
        }else{
          int off=(which==1)?32:64;
          QKV[off+j]=v0;QKV[96+off+j]=v1;QKV[192+off+j]=v2;QKV[288+off+j]=v3;
          float* cache=(which==1)?kc:vc;
          cache[(((size_t)l*64+(bs+0)*8+h)*64+t)*32+j]=v0;
          cache[(((size_t)l*64+(bs+1)*8+h)*64+t)*32+j]=v1;
          cache[(((size_t)l*64+(bs+2)*8+h)*64+t)*32+j]=v2;
          cache[(((size_t)l*64+(bs+3)*8+h)*64+t)*32+j]=v3;
        }
      }
    }
    __syncthreads();
    // causal scores: one wave per b
    {
      int bi=tid>>6,key=tid&63;
      float s=-3.0e38f;
      if(key<=t){
        float a=0.f;
        if(key==t){
#pragma unroll
          for(int i=0;i<8;++i){
            float4 q=F4(&QKV[bi*96+4*i]),k4=F4(&QKV[bi*96+32+4*i]);
            a+=D4(q,k4);
          }
        }else{
          const float4* kr=(const float4*)(kc+(((size_t)l*64+(bs+bi)*8+h)*64+key)*32);
#pragma unroll
          for(int i=0;i<8;++i){
            float4 q=F4(&QKV[bi*96+4*i]),k4=kr[i];
            a+=D4(q,k4);
          }
        }
        s=a*SCALE_;
      }
      float mx=wmax(s);
      float e=(key<=t)?expf(s-mx):0.f;
      float sm=wsum(e);
      SC[bi*64+key]=e/sm;
    }
    __syncthreads();
    // PV
    {
      int bi=tid>>6,lane=tid&63,gg=lane>>5,col=lane&31;
      float acc=0.f;
      int k0=gg*32,k1=min(k0+32,t+1);
      for(int k=k0;k<k1;++k){
        float vv=(k==t)?QKV[bi*96+64+col]
                       :vc[(((size_t)l*64+(bs+bi)*8+h)*64+k)*32+col];
        acc+=SC[bi*64+k]*vv;
      }
      PART[bi*64+gg*32+col]=acc;
    }
    __syncthreads();
    if(tid<128){
      int bi=tid>>5,col=tid&31;
      QKV[bi*96+col]=PART[bi*64+col]+PART[bi*64+32+col];  // o_h (overwrites q)
    }
    __syncthreads();
    // out-proj partial through sa_wo head slice
    {
      float a0=0.f,a1=0.f,a2=0.f,a3=0.f;
#pragma unroll
      for(int i=0;i<8;++i){
        float4 w=F4(&WO[c*36+4*i]);
        float4 o0=F4(&QKV[0*96+4*i]),o1=F4(&QKV[1*96+4*i]);
        float4 o2=F4(&QKV[2*96+4*i]),o3=F4(&QKV[3*96+4*i]);
        a0+=D4(w,o0);a1+=D4(w,o1);a2+=D4(w,o2);a3+=D4(w,o3);
      }
      ast(p1+(h*8+bs+0)*256+c,a0);
      ast(p1+(h*8+bs+1)*256+c,a1);
      ast(p1+(h*8+bs+2)*256+c,a2);
      ast(p1+(h*8+bs+3)*256+c,a3);
    }
    __syncthreads();
    if(tid==0){
      asti(f1+(bs+0)*8+h,fv);asti(f1+(bs+1)*8+h,fv);
      asti(f1+(bs+2)*8+h,fv);asti(f1+(bs+3)*8+h,fv);
    }
  }
}

// ============================ S2: cross-attention ===========================
DEV void role_s2(float* LDS,int rid,
    const float* __restrict__ enc,
    const float* __restrict__ ca_wqkv,const float* __restrict__ ca_bqkv,
    const float* __restrict__ ca_wo,
    const float* __restrict__ ln1_g,const float* __restrict__ ln1_b,
    const float* __restrict__ ln3_g,const float* __restrict__ ln3_b,
    const float* __restrict__ sa_bo,const float* __restrict__ emb_b,
    const int* f1,int* f2,
    const float* r3red,float* r1red,const float* p1,float* p2,const float* p5){
  const int tid=threadIdx.x;
  const int b=rid>>4,h=(rid>>1)&7,l=rid&1;
  float* WQ  =LDS;          // 32 x 260
  float* WO  =LDS+8320;     // 256 x 36
  float* MK  =LDS+17536;    // 256 x 36
  float* MV  =LDS+26752;    // 256 x 36
  float* XS  =LDS+35968;    // 256
  float* PS  =LDS+36224;    // 256
  float* PART=LDS+36480;    // 256
  float* QC  =LDS+36736;    // 48
  float* RED =LDS+36784;    // 16

  // --- prologue (a): temp-load the 64 K/V weight rows into [0,16640) ---
  for(int idx=tid;idx<64*64;idx+=256){
    int row=idx>>6,i4=idx&63;
    int grow=(row<32)?(256+h*32+row):(512+h*32+row-32);
    F4(&LDS[row*260+4*i4])=CF4(ca_wqkv+(size_t)l*196608+(size_t)grow*256+4*i4);
  }
  __syncthreads();
  // --- (b): compute this block's mem K/V slice into LDS ---
  for(int p=0;p<2;++p){
    int s=p*128+(tid>>1),kh=tid&1;
    float4 er[32];
#pragma unroll
    for(int i=0;i<32;++i) er[i]=CF4(enc+((size_t)(b*256+s))*256+kh*128+4*i);
    for(int out=0;out<64;++out){
      float a=0.f;
#pragma unroll
      for(int i=0;i<32;++i){
        float4 w=F4(&LDS[out*260+kh*128+4*i]);
        a+=D4(w,er[i]);
      }
      a+=__shfl_down(a,1,64);
      if(kh==0){
        if(out<32) MK[s*36+out]    =a+ca_bqkv[l*768+256+h*32+out];
        else       MV[s*36+out-32] =a+ca_bqkv[l*768+512+h*32+out-32];
      }
    }
  }
  __syncthreads();
  // --- (c): real stationary weights (overwrite temp region) ---
  for(int idx=tid;idx<32*64;idx+=256){
    int row=idx>>6,i4=idx&63;
    F4(&WQ[row*260+4*i4])=CF4(ca_wqkv+(size_t)l*196608+(size_t)(h*32+row)*256+4*i4);
  }
  for(int idx=tid;idx<256*8;idx+=256){
    int c=idx>>3,i=idx&7;
    F4(&WO[c*36+4*i])=CF4(ca_wo+(size_t)l*65536+(size_t)c*256+h*32+4*i);
  }
  __syncthreads();

  for(int t=0;t<64;++t){
    const int fv=2*t+l+1;
    const int c=tid;
    waitge(f1+b*8,8,fv);
    if(l==0){
      XS[c]=ald(p5+b*256+c)+ald(p5+2048+b*256+c)+emb_b[c]+pev(t,c);
    }else{
      XS[c]=ald(r3red+b*256+c);
      lnR(XS,1,ln3_g,ln3_b,RED);            // LN3 (layer0) -> x_l1
    }
    {
      float s=0.f;
#pragma unroll
      for(int h2=0;h2<8;++h2) s+=ald(p1+(h2*8+b)*256+c);
      float r1v=XS[c]+s+sa_bo[l*256+c];
      if(h==0) ast(r1red+l*2048+b*256+c,r1v);
      XS[c]=r1v;
    }
    lnR(XS,1,ln1_g+l*256,ln1_b+l*256,RED);
    // qc for head h
    if(tid<32){
      float a=0.f;
#pragma unroll
      for(int i=0;i<64;++i){
        float4 w=F4(&WQ[tid*260+4*i]),x4=F4(&XS[4*i]);
        a+=D4(w,x4);
      }
      QC[tid]=a+ca_bqkv[l*768+h*32+tid];
    }
    __syncthreads();
    // scores over 256 memory positions
    {
      float a=0.f;
#pragma unroll
      for(int i=0;i<8;++i){
        float4 k4=F4(&MK[tid*36+4*i]),q4=F4(&QC[4*i]);
        a+=D4(k4,q4);
      }
      float sv=a*SCALE_;
      int wid=tid>>6,lane=tid&63;
      float mx=wmax(sv);
      if(lane==0) RED[wid]=mx;
      __syncthreads();
      mx=fmaxf(fmaxf(RED[0],RED[1]),fmaxf(RED[2],RED[3]));
      float e=expf(sv-mx);
      float sm=wsum(e);
      if(lane==0) RED[4+wid]=sm;
      __syncthreads();
      sm=RED[4]+RED[5]+RED[6]+RED[7];
      PS[tid]=e/sm;
    }
    __syncthreads();
    // PV
    {
      int gg=tid>>5,col=tid&31;
      float acc=0.f;
      for(int s2=gg*32;s2<gg*32+32;++s2) acc+=PS[s2]*MV[s2*36+col];
      PART[gg*32+col]=acc;
    }
    __syncthreads();
    if(tid<32){
      float o=0.f;
#pragma unroll
      for(int g2=0;g2<8;++g2) o+=PART[g2*32+tid];
      QC[tid]=o;
    }
    __syncthreads();
    // proj partial through ca_wo head slice
    {
      float a=0.f;
#pragma unroll
      for(int i=0;i<8;++i){
        float4 w=F4(&WO[c*36+4*i]),o4=F4(&QC[4*i]);
        a+=D4(w,o4);
      }
      ast(p2+(h*8+b)*256+c,a);
    }
    __syncthreads();
    if(tid==0) asti(f2+b*8+h,fv);
  }
}

// ================================ S3: FFN ==================================
DEV void role_s3(float* LDS,int rid,
    const float* __restrict__ ffn_w1,const float* __restrict__ ffn_b1,
    const float* __restrict__ ffn_w2,
    const float* __restrict__ ln1_g,const float* __restrict__ ln1_b,
    const float* __restrict__ ln2_g,const float* __restrict__ ln2_b,
    const float* __restrict__ ca_bo,
    const int* f2,int* f3,
    const float* r1red,float* r2red,const float* p2,float* p3){
  const int tid=threadIdx.x;
  const int l=rid>>5,cg=(rid>>1)&15,bh=rid&1,bs=bh*4;
  float* W1 =LDS;           // 64 x 260
  float* W2T=LDS+16640;     // 64 x 260 (transposed: [k][c])
  float* X4 =LDS+33280;     // 4 x 256
  float* HH =LDS+34304;     // 4 x 68
  float* RED=LDS+34576;     // 16

  for(int idx=tid;idx<64*64;idx+=256){
    int row=idx>>6,i4=idx&63;
    F4(&W1[row*260+4*i4])=CF4(ffn_w1+(size_t)l*262144+(size_t)(cg*64+row)*256+4*i4);
  }
  for(int idx=tid;idx<256*16;idx+=256){
    int cc=idx>>4,k4=idx&15;
    float4 w=CF4(ffn_w2+(size_t)l*262144+(size_t)cc*1024+cg*64+4*k4);
    W2T[(4*k4+0)*260+cc]=w.x;W2T[(4*k4+1)*260+cc]=w.y;
    W2T[(4*k4+2)*260+cc]=w.z;W2T[(4*k4+3)*260+cc]=w.w;
  }
  __syncthreads();

  for(int t=0;t<64;++t){
    const int fv=2*t+l+1;
    if(tid<32){
      int bi=tid>>3,h2=tid&7;
      const int* fp=f2+(bs+bi)*8+h2;
      while(aldi(fp)<fv){}
    }
    __syncthreads();
    const int c=tid;
    for(int bi=0;bi<4;++bi) X4[bi*256+c]=ald(r1red+l*2048+(bs+bi)*256+c);
    lnR(X4,4,ln1_g+l*256,ln1_b+l*256,RED);
    for(int bi=0;bi<4;++bi){
      float s=0.f;
#pragma unroll
      for(int h2=0;h2<8;++h2) s+=ald(p2+(h2*8+bs+bi)*256+c);
      float v=X4[bi*256+c]+s+ca_bo[l*256+c];
      if(cg==0) ast(r2red+l*2048+(bs+bi)*256+c,v);
      X4[bi*256+c]=v;
    }
    lnR(X4,4,ln2_g+l*256,ln2_b+l*256,RED);
    // FFN1: 64 rows x 4 b, K-split 4
    {
      int row=tid>>2,kq=tid&3;
      float a0=0.f,a1=0.f,a2=0.f,a3=0.f;
#pragma unroll
      for(int i=0;i<16;++i){
        float4 w=F4(&W1[row*260+kq*64+4*i]);
        float4 x0=F4(&X4[0*256+kq*64+4*i]),x1=F4(&X4[1*256+kq*64+4*i]);
        float4 x2=F4(&X4[2*256+kq*64+4*i]),x3=F4(&X4[3*256+kq*64+4*i]);
        a0+=D4(w,x0);a1+=D4(w,x1);a2+=D4(w,x2);a3+=D4(w,x3);
      }
      a0+=__shfl_down(a0,2,64);a0+=__shfl_down(a0,1,64);
      a1+=__shfl_down(a1,2,64);a1+=__shfl_down(a1,1,64);
      a2+=__shfl_down(a2,2,64);a2+=__shfl_down(a2,1,64);
      a3+=__shfl_down(a3,2,64);a3+=__shfl_down(a3,1,64);
      if(kq==0){
        float b1v=ffn_b1[l*1024+cg*64+row];
        HH[0*68+row]=fmaxf(a0+b1v,0.f);HH[1*68+row]=fmaxf(a1+b1v,0.f);
        HH[2*68+row]=fmaxf(a2+b1v,0.f);HH[3*68+row]=fmaxf(a3+b1v,0.f);
      }
    }
    __syncthreads();
    // FFN2 partial over this 64-wide k-slice, all 256 out cols
    {
      int chunk=tid&63,bi=tid>>6;
      float ax=0.f,ay=0.f,az=0.f,aw=0.f;
      for(int k=0;k<64;++k){
        float4 w=F4(&W2T[k*260+4*chunk]);
        float hv=HH[bi*68+k];
        ax+=w.x*hv;ay+=w.y*hv;az+=w.z*hv;aw+=w.w*hv;
      }
      float* dst=p3+(size_t)l*32768+(size_t)(cg*8+bs+bi)*256+4*chunk;
      ast(dst+0,ax);ast(dst+1,ay);ast(dst+2,az);ast(dst+3,aw);
    }
    __syncthreads();
    if(tid==0) asti(f3+l*32+cg*2+bh,t+1);
  }
}

// ====================== S5a: head proj + BN + ReLU =========================
DEV void role_s5a(float* LDS,int cg,
    const float* __restrict__ op_w1,const float* __restrict__ op_b1,
    const float* __restrict__ bn_g,const float* __restrict__ bn_b,
    const float* __restrict__ ln2_g,const float* __restrict__ ln2_b,
    const float* __restrict__ ln3_g,const float* __restrict__ ln3_b,
    const float* __restrict__ ffn_b2,
    const int* f3,int* f5a,
    const float* r2red,const float* p3,float* ybuf){
  const int tid=threadIdx.x;
  float* W  =LDS;           // 64 x 260
  float* X8 =LDS+16640;     // 8 x 256
  float* RED=LDS+18688;     // 16

  for(int idx=tid;idx<64*64;idx+=256){
    int row=idx>>6,i4=idx&63;
    F4(&W[row*260+4*i4])=CF4(op_w1+(size_t)(cg*64+row)*256+4*i4);
  }
  __syncthreads();

  for(int t=0;t<64;++t){
    waitge(f3+32,32,t+1);   // layer-1 S3 flags
    const int c=tid;
    for(int bi=0;bi<8;++bi) X8[bi*256+c]=ald(r2red+2048+bi*256+c);
    lnR(X8,8,ln2_g+256,ln2_b+256,RED);
    for(int bi=0;bi<8;++bi){
      float s=0.f;
#pragma unroll
      for(int cgi=0;cgi<16;++cgi) s+=ald(p3+32768+(cgi*8+bi)*256+c);
      X8[bi*256+c]+=s+ffn_b2[256+c];
    }
    lnR(X8,8,ln3_g+256,ln3_b+256,RED);
    {
      int row=tid>>2,kq=tid&3;
      float acc[8]={0.f,0.f,0.f,0.f,0.f,0.f,0.f,0.f};
#pragma unroll
      for(int i=0;i<16;++i){
        float4 w=F4(&W[row*260+kq*64+4*i]);
#pragma unroll
        for(int bi=0;bi<8;++bi){
          float4 xa=F4(&X8[bi*256+kq*64+4*i]);
          acc[bi]+=D4(w,xa);
        }
      }
#pragma unroll
      for(int bi=0;bi<8;++bi){
        acc[bi]+=__shfl_down(acc[bi],2,64);
        acc[bi]+=__shfl_down(acc[bi],1,64);
      }
      if(kq==0){
        int col=cg*64+row;
        float gg=BNS*bn_g[col],bb=bn_b[col],ob=op_b1[col];
#pragma unroll
        for(int bi=0;bi<8;++bi){
          float y=fmaxf((acc[bi]+ob)*gg+bb,0.f);
          ast(ybuf+bi*256+col,y);
        }
      }
    }
    __syncthreads();
    if(tid==0) asti(f5a+cg,t+1);
  }
}

// ============== S5b: logits + output write + emb partial (p5) ==============
DEV void role_s5b(float* LDS,int half,
    const float* __restrict__ op_w2,const float* __restrict__ op_b2,
    const float* __restrict__ emb_w,
    const int* f5a,int* f5b,
    const float* ybuf,float* p5,float* outp){
  const int tid=threadIdx.x;
  float* W  =LDS;           // 64 x 260  (op_w2 rows half*64..)
  float* EMB=LDS+16640;     // 256 x 68  (emb_w cols half*64..)
  float* Y8 =LDS+34048;     // 8 x 256
  float* LG =LDS+36096;     // 8 x 68

  for(int idx=tid;idx<64*64;idx+=256){
    int row=idx>>6,i4=idx&63;
    F4(&W[row*260+4*i4])=CF4(op_w2+(size_t)(half*64+row)*256+4*i4);
  }
  for(int idx=tid;idx<256*16;idx+=256){
    int d=idx>>4,k4=idx&15;
    F4(&EMB[d*68+4*k4])=CF4(emb_w+(size_t)d*128+half*64+4*k4);
  }
  __syncthreads();

  for(int t=0;t<64;++t){
    waitge(f5a,4,t+1);
    const int c=tid;
    for(int bi=0;bi<8;++bi) Y8[bi*256+c]=ald(ybuf+bi*256+c);
    __syncthreads();
    // logits (64 cols x 8 b, K-split 4)
    {
      int cc=tid>>2,kq=tid&3;
      float acc[8]={0.f,0.f,0.f,0.f,0.f,0.f,0.f,0.f};
#pragma unroll
      for(int i=0;i<16;++i){
        float4 w=F4(&W[cc*260+kq*64+4*i]);
#pragma unroll
        for(int bi=0;bi<8;++bi){
          float4 ya=F4(&Y8[bi*256+kq*64+4*i]);
          acc[bi]+=D4(w,ya);
        }
      }
#pragma unroll
      for(int bi=0;bi<8;++bi){
        acc[bi]+=__shfl_down(acc[bi],2,64);
        acc[bi]+=__shfl_down(acc[bi],1,64);
      }
      if(kq==0){
        int col=half*64+cc;
        float ob=op_b2[col];
#pragma unroll
        for(int bi=0;bi<8;++bi){
          float v=acc[bi]+ob;
          outp[((size_t)bi*64+t)*128+col]=v;
          LG[bi*68+cc]=v;
        }
      }
    }
    __syncthreads();
    // emb partial over this half's 64 logits -> p5[half]
    {
      int d=tid;
      float acc[8]={0.f,0.f,0.f,0.f,0.f,0.f,0.f,0.f};
#pragma unroll
      for(int i=0;i<16;++i){
        float4 w=F4(&EMB[d*68+4*i]);
#pragma unroll
        for(int bi=0;bi<8;++bi){
          float4 lgv=F4(&LG[bi*68+4*i]);
          acc[bi]+=D4(w,lgv);
        }
      }
#pragma unroll
      for(int bi=0;bi<8;++bi) ast(p5+half*2048+bi*256+d,acc[bi]);
    }
    __syncthreads();
    if(tid==0) asti(f5b+half,t+1);
  }
}

// ---------------------------------------------------------------------------

__global__ void __launch_bounds__(256,1) k_decode(
    const float* enc,const float* emb_w,const float* emb_b,
    const float* sa_wqkv,const float* sa_bqkv,const float* sa_wo,const float* sa_bo,
    const float* ca_wqkv,const float* ca_bqkv,const float* ca_wo,const float* ca_bo,
    const float* ln1_g,const float* ln1_b,const float* ln2_g,const float* ln2_b,
    const float* ffn_w1,const float* ffn_b1,const float* ffn_w2,const float* ffn_b2,
    const float* ln3_g,const float* ln3_b,
    const float* op_w1,const float* op_b1,const float* bn_g,const float* bn_b,
    const float* op_w2,const float* op_b2,
    int* f1,int* f2,int* f3,int* f5a,int* f5b,
    float* p5,float* kc,float* vc,float* r1red,float* r2red,float* r3red,
    float* p1,float* p2,float* p3,float* ybuf,float* outp){
  __shared__ __align__(16) float LDS[DYNF];
  const int blk=blockIdx.x;
  if(blk<32){
    role_s1(LDS,blk,sa_wqkv,sa_bqkv,sa_wo,ln2_g,ln2_b,ln3_g,ln3_b,ffn_b2,emb_b,
            f1,f3,f5b,kc,vc,r2red,r3red,p3,p1,p5);
  }else if(blk<160){
    role_s2(LDS,blk-32,enc,ca_wqkv,ca_bqkv,ca_wo,ln1_g,ln1_b,ln3_g,ln3_b,sa_bo,emb_b,
            f1,f2,r3red,r1red,p1,p2,p5);
  }else if(blk<224){
    role_s3(LDS,blk-160,ffn_w1,ffn_b1,ffn_w2,ln1_g,ln1_b,ln2_g,ln2_b,ca_bo,
            f2,f3,r1red,r2red,p2,p3);
  }else if(blk<228){
    role_s5a(LDS,blk-224,op_w1,op_b1,bn_g,bn_b,ln2_g,ln2_b,ln3_g,ln3_b,ffn_b2,
             f3,f5a,r2red,p3,ybuf);
  }else{
    role_s5b(LDS,blk-228,op_w2,op_b2,emb_w,f5a,f5b,ybuf,p5,outp);
  }
}

// ---------------------------------------------------------------------------

extern "C" void kernel_launch(void* const* d_in, const int* in_sizes, int n_in,
                              void* d_out, int out_size, void* d_ws, size_t ws_size,
                              hipStream_t stream) {
  (void)in_sizes;(void)n_in;(void)out_size;(void)ws_size;
  const float* enc     =(const float*)d_in[0];
  const float* emb_w   =(const float*)d_in[1];
  const float* emb_b   =(const float*)d_in[2];
  const float* sa_wqkv =(const float*)d_in[3];
  const float* sa_bqkv =(const float*)d_in[4];
  const float* sa_wo   =(const float*)d_in[5];
  const float* sa_bo   =(const float*)d_in[6];
  const float* ca_wqkv =(const float*)d_in[7];
  const float* ca_bqkv =(const float*)d_in[8];
  const float* ca_wo   =(const float*)d_in[9];
  const float* ca_bo   =(const float*)d_in[10];
  const float* ln1_g   =(const float*)d_in[11];
  const float* ln1_b   =(const float*)d_in[12];
  const float* ln2_g   =(const float*)d_in[13];
  const float* ln2_b   =(const float*)d_in[14];
  const float* ffn_w1  =(const float*)d_in[15];
  const float* ffn_b1  =(const float*)d_in[16];
  const float* ffn_w2  =(const float*)d_in[17];
  const float* ffn_b2  =(const float*)d_in[18];
  const float* ln3_g   =(const float*)d_in[19];
  const float* ln3_b   =(const float*)d_in[20];
  const float* op_w1   =(const float*)d_in[21];
  const float* op_b1   =(const float*)d_in[22];
  const float* bn_g    =(const float*)d_in[23];
  const float* bn_b    =(const float*)d_in[24];
  const float* op_w2   =(const float*)d_in[25];
  const float* op_b2   =(const float*)d_in[26];

  float* out=(float*)d_out;

  // int flag region (256 ints) + p5 (4096 floats) must be zeroed each call.
  int* I=(int*)d_ws;
  int* f1 =I;        // 64
  int* f2 =I+64;     // 64
  int* f3 =I+128;    // 64  ([l*32 + cg*2 + bh])
  int* f5a=I+192;    // 4
  int* f5b=I+196;    // 2
  hipMemsetAsync(d_ws,0,256*4+4096*4,stream);

  float* F=(float*)d_ws+256;
  float* p5   =F;               // 2 x 8 x 256
  float* kc   =p5+4096;         // 2 x 8 x 8 x 64 x 32
  float* vc   =kc+262144;
  float* r1red=vc+262144;       // 2 x 8 x 256
  float* r2red=r1red+4096;      // 2 x 8 x 256
  float* r3red=r2red+4096;      // 8 x 256
  float* p1   =r3red+2048;      // 8h x 8b x 256
  float* p2   =p1+16384;        // 8h x 8b x 256
  float* p3   =p2+16384;        // 2 x 16 x 8 x 256
  float* ybuf =p3+65536;        // 8 x 256

  k_decode<<<230,256,0,stream>>>(
      enc,emb_w,emb_b,sa_wqkv,sa_bqkv,sa_wo,sa_bo,
      ca_wqkv,ca_bqkv,ca_wo,ca_bo,ln1_g,ln1_b,ln2_g,ln2_b,
      ffn_w1,ffn_b1,ffn_w2,ffn_b2,ln3_g,ln3_b,
      op_w1,op_b1,bn_g,bn_b,op_w2,op_b2,
      f1,f2,f3,f5a,f5b,
      p5,kc,vc,r1red,r2red,r3red,p1,p2,p3,ybuf,out);
}

// Round 8
// 4806.156 us; speedup vs baseline: 1.4264x; 1.4264x over previous
//
#include <hip/hip_runtime.h>
#include <math.h>

// ---------------------------------------------------------------------------
// TransformerDecoder: weight-stationary persistent dataflow decode, v2 sync.
// B=8, S_SRC=256, T=64, D=256, H=8, HD=32, DFF=1024, NC=128, L=2. fp32.
// 232 blocks (1/CU):
//   S1 [0,32):   (h,l,bhalf)  SA qkv+attn+o-proj partial   (weights in LDS)
//   S2 [32,160): (b,h,l)      p1-reduce, CA (memKV in LDS), proj partial
//   S3 [160,224):(l,cg16,bh)  p2-reduce, FFN1 + FFN2 partial (weights in LDS)
//   HEAD[224,232):(b)         r3(l1), op_w1+BN+relu, logits, out, emb->xrow
// Sync: per-producer flags padded to one 128B line each; consumer wave-0
// polls all flags in ONE wave instruction + __all + s_sleep backoff.
// All cross-block data via agent-scope relaxed atomics (MALL-coherent).
// ---------------------------------------------------------------------------

#define EPS_ 1e-5f
#define SCALE_ 0.17677669529663687f   // 1/sqrt(32)
#define BNS 0.99999500003749969f      // 1/sqrt(1+1e-5)
#define DEV __device__ __forceinline__
#define DYNF 36864                     // LDS floats per block (147456 B)

#define D4(a,b) ((a).x*(b).x+(a).y*(b).y+(a).z*(b).z+(a).w*(b).w)
#define F4(p)  (*(float4*)(p))
#define CF4(p) (*(const float4*)(p))

DEV float ald(const float* p){return __hip_atomic_load(p,__ATOMIC_RELAXED,__HIP_MEMORY_SCOPE_AGENT);}
DEV void  ast(float* p,float v){__hip_atomic_store(p,v,__ATOMIC_RELAXED,__HIP_MEMORY_SCOPE_AGENT);}
DEV int   aldi(const int* p){return __hip_atomic_load(p,__ATOMIC_RELAXED,__HIP_MEMORY_SCOPE_AGENT);}
DEV void  asti(int* p,int v){__hip_atomic_store(p,v,__ATOMIC_RELAXED,__HIP_MEMORY_SCOPE_AGENT);}

DEV float wsum(float v){
#pragma unroll
  for(int o=32;o;o>>=1) v+=__shfl_xor(v,o,64);
  return v;
}
DEV float wmax(float v){
#pragma unroll
  for(int o=32;o;o>>=1) v=fmaxf(v,__shfl_xor(v,o,64));
  return v;
}

DEV float pev(int t,int c){
  float dv=expf((float)(c&~1)*(-9.210340371976184f/256.f)); // ln(10000)
  float a=(float)t*dv;
  return (c&1)?cosf(a):sinf(a);
}

// wave-0 polls n (<=64) flags, each padded to its own 128B line (stride 32 ints)
DEV void waitflags(const int* base,int n,int s){
  if((int)threadIdx.x<64){
    const int* p=base+threadIdx.x*32;
    bool need=(int)threadIdx.x<n;
    while(true){
      int v=need?aldi(p):0x7fffffff;
      if(__all(v>=s)) break;
      __builtin_amdgcn_s_sleep(1);
    }
  }
  __syncthreads();
}

// In-place LayerNorm of R rows x 256 in LDS (stride 256); 256 threads.
DEV void lnR(float* x,int R,const float* __restrict__ g,const float* __restrict__ bv,float* red){
  __syncthreads();
  int tid=threadIdx.x,wid=tid>>6,lane=tid&63;
  for(int r=wid;r<R;r+=4){
    float s=0.f,s2=0.f;
    for(int i=lane;i<256;i+=64){float v=x[r*256+i];s+=v;s2+=v*v;}
    s=wsum(s);s2=wsum(s2);
    if(lane==0){float m=s*(1.f/256.f);red[r]=m;red[8+r]=rsqrtf(s2*(1.f/256.f)-m*m+EPS_);}
  }
  __syncthreads();
  for(int i=tid;i<R*256;i+=256){int r=i>>8,c=i&255;x[i]=(x[i]-red[r])*red[8+r]*g[c]+bv[c];}
  __syncthreads();
}

// ============================ S1: self-attention ============================
DEV void role_s1(float* LDS,int rid,
    const float* __restrict__ sa_wqkv,const float* __restrict__ sa_bqkv,
    const float* __restrict__ sa_wo,
    const float* __restrict__ ln2_g,const float* __restrict__ ln2_b,
    const float* __restrict__ ln3_g,const float* __restrict__ ln3_b,
    const float* __restrict__ ffn_b2,const float* __restrict__ emb_b,
    int* F1,const int* F3,const int* FX0,
    float* kc,float* vc,const float* r2red,float* r3red,
    const float* p3,float* p1,const float* xrow){
  const int tid=threadIdx.x;
  const int h=rid>>2, l=(rid>>1)&1, bs=(rid&1)*4;
  float* W   =LDS;          // 96 x 260
  float* WO  =LDS+24960;    // 256 x 36
  float* XS  =LDS+34176;    // 4 x 256
  float* QKV =LDS+35200;    // 4 x 96 (q|k|v per b)
  float* SC  =LDS+35584;    // 4 x 64
  float* PART=LDS+35840;    // 4 x 64
  float* RED =LDS+36096;    // 16

  for(int idx=tid;idx<96*64;idx+=256){
    int row=idx>>6,i4=idx&63,which=row>>5,j=row&31;
    F4(&W[row*260+4*i4])=CF4(sa_wqkv+(size_t)l*196608+((size_t)(which*256+h*32+j))*256+4*i4);
  }
  for(int idx=tid;idx<256*8;idx+=256){
    int c=idx>>3,i=idx&7;
    F4(&WO[c*36+4*i])=CF4(sa_wo+(size_t)l*65536+(size_t)c*256+h*32+4*i);
  }
  __syncthreads();

  for(int t=0;t<64;++t){
    const int c=tid;
    if(l==0){
      waitflags(FX0+bs*32,4,t);
      float xb=emb_b[c]+pev(t,c);
      for(int bi=0;bi<4;++bi) XS[bi*256+c]=ald(xrow+(bs+bi)*256+c)+xb;
      __syncthreads();
    }else{
      waitflags(F3+bs*16*32,64,t+1);   // layer-0 S3 flags, 4 b x 16 cg
      for(int bi=0;bi<4;++bi) XS[bi*256+c]=ald(r2red+(bs+bi)*256+c);
      lnR(XS,4,ln2_g,ln2_b,RED);            // LN2 (layer0)
      for(int bi=0;bi<4;++bi){
        int b=bs+bi;
        float s=0.f;
#pragma unroll
        for(int cg=0;cg<16;++cg) s+=ald(p3+(cg*8+b)*256+c);
        float r3v=XS[bi*256+c]+s+ffn_b2[c];
        if(h==0) ast(r3red+b*256+c,r3v);
        XS[bi*256+c]=r3v;
      }
      lnR(XS,4,ln3_g,ln3_b,RED);            // LN3 (layer0)
    }
    // qkv for current token (96 rows x 4 b, K-split 2)
    if(tid<192){
      int row=tid>>1,kq=tid&1;
      float a0=0.f,a1=0.f,a2=0.f,a3=0.f;
#pragma unroll
      for(int i=0;i<32;++i){
        float4 w=F4(&W[row*260+kq*128+4*i]);
        float4 x0=F4(&XS[0*256+kq*128+4*i]),x1=F4(&XS[1*256+kq*128+4*i]);
        float4 x2=F4(&XS[2*256+kq*128+4*i]),x3=F4(&XS[3*256+kq*128+4*i]);
        a0+=D4(w,x0);a1+=D4(w,x1);a2+=D4(w,x2);a3+=D4(w,x3);
      }
      a0+=__shfl_down(a0,1,64);a1+=__shfl_down(a1,1,64);
      a2+=__shfl_down(a2,1,64);a3+=__shfl_down(a3,1,64);
      if(kq==0){
        int which=row>>5,j=row&31;
        float bias=sa_bqkv[l*768+which*256+h*32+j];
        float v0=a0+bias,v1=a1+bias,v2=a2+bias,v3=a3+bias;
        if(which==0){
          QKV[j]=v0;QKV[96+j]=v1;QKV[192+j]=v2;QKV[288+j]=v3;
        }else{
          int off=(which==1)?32:64;
          QKV[off+j]=v0;QKV[96+off+j]=v1;QKV[192+off+j]=v2;QKV[288+off+j]=v3;
          float* cache=(which==1)?kc:vc;
          cache[(((size_t)l*64+(bs+0)*8+h)*64+t)*32+j]=v0;
          cache[(((size_t)l*64+(bs+1)*8+h)*64+t)*32+j]=v1;
          cache[(((size_t)l*64+(bs+2)*8+h)*64+t)*32+j]=v2;
          cache[(((size_t)l*64+(bs+3)*8+h)*64+t)*32+j]=v3;
        }
      }
    }
    __syncthreads();
    // causal scores: one wave per b
    {
      int bi=tid>>6,key=tid&63;
      float s=-3.0e38f;
      if(key<=t){
        float a=0.f;
        if(key==t){
#pragma unroll
          for(int i=0;i<8;++i){
            float4 q=F4(&QKV[bi*96+4*i]),k4=F4(&QKV[bi*96+32+4*i]);
            a+=D4(q,k4);
          }
        }else{
          const float4* kr=(const float4*)(kc+(((size_t)l*64+(bs+bi)*8+h)*64+key)*32);
#pragma unroll
          for(int i=0;i<8;++i){
            float4 q=F4(&QKV[bi*96+4*i]),k4=kr[i];
            a+=D4(q,k4);
          }
        }
        s=a*SCALE_;
      }
      float mx=wmax(s);
      float e=(key<=t)?expf(s-mx):0.f;
      float sm=wsum(e);
      SC[bi*64+key]=e/sm;
    }
    __syncthreads();
    // PV
    {
      int bi=tid>>6,lane=tid&63,gg=lane>>5,col=lane&31;
      float acc=0.f;
      int k0=gg*32,k1=min(k0+32,t+1);
      for(int k=k0;k<k1;++k){
        float vv=(k==t)?QKV[bi*96+64+col]
                       :vc[(((size_t)l*64+(bs+bi)*8+h)*64+k)*32+col];
        acc+=SC[bi*64+k]*vv;
      }
      PART[bi*64+gg*32+col]=acc;
    }
    __syncthreads();
    if(tid<128){
      int bi=tid>>5,col=tid&31;
      QKV[bi*96+col]=PART[bi*64+col]+PART[bi*64+32+col];  // o_h
    }
    __syncthreads();
    // out-proj partial through sa_wo head slice
    {
      float a0=0.f,a1=0.f,a2=0.f,a3=0.f;
#pragma unroll
      for(int i=0;i<8;++i){
        float4 w=F4(&WO[c*36+4*i]);
        float4 o0=F4(&QKV[0*96+4*i]),o1=F4(&QKV[1*96+4*i]);
        float4 o2=F4(&QKV[2*96+4*i]),o3=F4(&QKV[3*96+4*i]);
        a0+=D4(w,o0);a1+=D4(w,o1);a2+=D4(w,o2);a3+=D4(w,o3);
      }
      ast(p1+(h*8+bs+0)*256+c,a0);
      ast(p1+(h*8+bs+1)*256+c,a1);
      ast(p1+(h*8+bs+2)*256+c,a2);
      ast(p1+(h*8+bs+3)*256+c,a3);
    }
    __syncthreads();   // drain stores before flags
    if(tid<4) asti(F1+((l*8+bs+tid)*8+h)*32,t+1);
  }
}

// ============================ S2: cross-attention ===========================
DEV void role_s2(float* LDS,int rid,
    const float* __restrict__ enc,
    const float* __restrict__ ca_wqkv,const float* __restrict__ ca_bqkv,
    const float* __restrict__ ca_wo,
    const float* __restrict__ ln1_g,const float* __restrict__ ln1_b,
    const float* __restrict__ ln3_g,const float* __restrict__ ln3_b,
    const float* __restrict__ sa_bo,const float* __restrict__ emb_b,
    const int* F1,int* F2,
    const float* r3red,float* r1red,const float* p1,float* p2,const float* xrow){
  const int tid=threadIdx.x;
  const int b=rid>>4,h=(rid>>1)&7,l=rid&1;
  float* WQ  =LDS;          // 32 x 260
  float* WO  =LDS+8320;     // 256 x 36
  float* MK  =LDS+17536;    // 256 x 36
  float* MV  =LDS+26752;    // 256 x 36
  float* XS  =LDS+35968;    // 256
  float* PS  =LDS+36224;    // 256
  float* PART=LDS+36480;    // 256
  float* QC  =LDS+36736;    // 48
  float* RED =LDS+36784;    // 16

  // prologue (a): temp-load 64 K/V weight rows
  for(int idx=tid;idx<64*64;idx+=256){
    int row=idx>>6,i4=idx&63;
    int grow=(row<32)?(256+h*32+row):(512+h*32+row-32);
    F4(&LDS[row*260+4*i4])=CF4(ca_wqkv+(size_t)l*196608+(size_t)grow*256+4*i4);
  }
  __syncthreads();
  // (b): compute mem K/V slice into LDS
  for(int p=0;p<2;++p){
    int s=p*128+(tid>>1),kh=tid&1;
    float4 er[32];
#pragma unroll
    for(int i=0;i<32;++i) er[i]=CF4(enc+((size_t)(b*256+s))*256+kh*128+4*i);
    for(int out=0;out<64;++out){
      float a=0.f;
#pragma unroll
      for(int i=0;i<32;++i){
        float4 w=F4(&LDS[out*260+kh*128+4*i]);
        a+=D4(w,er[i]);
      }
      a+=__shfl_down(a,1,64);
      if(kh==0){
        if(out<32) MK[s*36+out]    =a+ca_bqkv[l*768+256+h*32+out];
        else       MV[s*36+out-32] =a+ca_bqkv[l*768+512+h*32+out-32];
      }
    }
  }
  __syncthreads();
  // (c): stationary weights
  for(int idx=tid;idx<32*64;idx+=256){
    int row=idx>>6,i4=idx&63;
    F4(&WQ[row*260+4*i4])=CF4(ca_wqkv+(size_t)l*196608+(size_t)(h*32+row)*256+4*i4);
  }
  for(int idx=tid;idx<256*8;idx+=256){
    int c=idx>>3,i=idx&7;
    F4(&WO[c*36+4*i])=CF4(ca_wo+(size_t)l*65536+(size_t)c*256+h*32+4*i);
  }
  __syncthreads();

  for(int t=0;t<64;++t){
    const int c=tid;
    waitflags(F1+(l*8+b)*8*32,8,t+1);
    if(l==0){
      XS[c]=ald(xrow+b*256+c)+emb_b[c]+pev(t,c);
    }else{
      XS[c]=ald(r3red+b*256+c);
      lnR(XS,1,ln3_g,ln3_b,RED);            // LN3 (layer0) -> x_l1
    }
    {
      float s=0.f;
#pragma unroll
      for(int h2=0;h2<8;++h2) s+=ald(p1+(h2*8+b)*256+c);
      float r1v=XS[c]+s+sa_bo[l*256+c];
      if(h==0) ast(r1red+l*2048+b*256+c,r1v);
      XS[c]=r1v;
    }
    lnR(XS,1,ln1_g+l*256,ln1_b+l*256,RED);
    if(tid<32){
      float a=0.f;
#pragma unroll
      for(int i=0;i<64;++i){
        float4 w=F4(&WQ[tid*260+4*i]),x4=F4(&XS[4*i]);
        a+=D4(w,x4);
      }
      QC[tid]=a+ca_bqkv[l*768+h*32+tid];
    }
    __syncthreads();
    {
      float a=0.f;
#pragma unroll
      for(int i=0;i<8;++i){
        float4 k4=F4(&MK[tid*36+4*i]),q4=F4(&QC[4*i]);
        a+=D4(k4,q4);
      }
      float sv=a*SCALE_;
      int wid=tid>>6,lane=tid&63;
      float mx=wmax(sv);
      if(lane==0) RED[wid]=mx;
      __syncthreads();
      mx=fmaxf(fmaxf(RED[0],RED[1]),fmaxf(RED[2],RED[3]));
      float e=expf(sv-mx);
      float sm=wsum(e);
      if(lane==0) RED[4+wid]=sm;
      __syncthreads();
      sm=RED[4]+RED[5]+RED[6]+RED[7];
      PS[tid]=e/sm;
    }
    __syncthreads();
    {
      int gg=tid>>5,col=tid&31;
      float acc=0.f;
      for(int s2=gg*32;s2<gg*32+32;++s2) acc+=PS[s2]*MV[s2*36+col];
      PART[gg*32+col]=acc;
    }
    __syncthreads();
    if(tid<32){
      float o=0.f;
#pragma unroll
      for(int g2=0;g2<8;++g2) o+=PART[g2*32+tid];
      QC[tid]=o;
    }
    __syncthreads();
    {
      float a=0.f;
#pragma unroll
      for(int i=0;i<8;++i){
        float4 w=F4(&WO[c*36+4*i]),o4=F4(&QC[4*i]);
        a+=D4(w,o4);
      }
      ast(p2+(h*8+b)*256+c,a);
    }
    __syncthreads();
    if(tid==0) asti(F2+((l*8+b)*8+h)*32,t+1);
  }
}

// ================================ S3: FFN ==================================
DEV void role_s3(float* LDS,int rid,
    const float* __restrict__ ffn_w1,const float* __restrict__ ffn_b1,
    const float* __restrict__ ffn_w2,
    const float* __restrict__ ln1_g,const float* __restrict__ ln1_b,
    const float* __restrict__ ln2_g,const float* __restrict__ ln2_b,
    const float* __restrict__ ca_bo,
    const int* F2,int* F3,
    const float* r1red,float* r2red,const float* p2,float* p3){
  const int tid=threadIdx.x;
  const int l=rid>>5,cg=(rid>>1)&15,bh=rid&1,bs=bh*4;
  float* W1 =LDS;           // 64 x 260
  float* W2T=LDS+16640;     // 64 x 260 (transposed: [k][c])
  float* X4 =LDS+33280;     // 4 x 256
  float* HH =LDS+34304;     // 4 x 68
  float* RED=LDS+34576;     // 16

  for(int idx=tid;idx<64*64;idx+=256){
    int row=idx>>6,i4=idx&63;
    F4(&W1[row*260+4*i4])=CF4(ffn_w1+(size_t)l*262144+(size_t)(cg*64+row)*256+4*i4);
  }
  for(int idx=tid;idx<256*16;idx+=256){
    int cc=idx>>4,k4=idx&15;
    float4 w=CF4(ffn_w2+(size_t)l*262144+(size_t)cc*1024+cg*64+4*k4);
    W2T[(4*k4+0)*260+cc]=w.x;W2T[(4*k4+1)*260+cc]=w.y;
    W2T[(4*k4+2)*260+cc]=w.z;W2T[(4*k4+3)*260+cc]=w.w;
  }
  __syncthreads();

  for(int t=0;t<64;++t){
    waitflags(F2+(l*8+bs)*8*32,32,t+1);   // 4 b x 8 h
    const int c=tid;
    for(int bi=0;bi<4;++bi) X4[bi*256+c]=ald(r1red+l*2048+(bs+bi)*256+c);
    lnR(X4,4,ln1_g+l*256,ln1_b+l*256,RED);
    for(int bi=0;bi<4;++bi){
      float s=0.f;
#pragma unroll
      for(int h2=0;h2<8;++h2) s+=ald(p2+(h2*8+bs+bi)*256+c);
      float v=X4[bi*256+c]+s+ca_bo[l*256+c];
      if(cg==0) ast(r2red+l*2048+(bs+bi)*256+c,v);
      X4[bi*256+c]=v;
    }
    lnR(X4,4,ln2_g+l*256,ln2_b+l*256,RED);
    // FFN1: 64 rows x 4 b, K-split 4
    {
      int row=tid>>2,kq=tid&3;
      float a0=0.f,a1=0.f,a2=0.f,a3=0.f;
#pragma unroll
      for(int i=0;i<16;++i){
        float4 w=F4(&W1[row*260+kq*64+4*i]);
        float4 x0=F4(&X4[0*256+kq*64+4*i]),x1=F4(&X4[1*256+kq*64+4*i]);
        float4 x2=F4(&X4[2*256+kq*64+4*i]),x3=F4(&X4[3*256+kq*64+4*i]);
        a0+=D4(w,x0);a1+=D4(w,x1);a2+=D4(w,x2);a3+=D4(w,x3);
      }
      a0+=__shfl_down(a0,2,64);a0+=__shfl_down(a0,1,64);
      a1+=__shfl_down(a1,2,64);a1+=__shfl_down(a1,1,64);
      a2+=__shfl_down(a2,2,64);a2+=__shfl_down(a2,1,64);
      a3+=__shfl_down(a3,2,64);a3+=__shfl_down(a3,1,64);
      if(kq==0){
        float b1v=ffn_b1[l*1024+cg*64+row];
        HH[0*68+row]=fmaxf(a0+b1v,0.f);HH[1*68+row]=fmaxf(a1+b1v,0.f);
        HH[2*68+row]=fmaxf(a2+b1v,0.f);HH[3*68+row]=fmaxf(a3+b1v,0.f);
      }
    }
    __syncthreads();
    // FFN2 partial over this 64-wide k-slice, all 256 out cols
    {
      int chunk=tid&63,bi=tid>>6;
      float ax=0.f,ay=0.f,az=0.f,aw=0.f;
      for(int k=0;k<64;++k){
        float4 w=F4(&W2T[k*260+4*chunk]);
        float hv=HH[bi*68+k];
        ax+=w.x*hv;ay+=w.y*hv;az+=w.z*hv;aw+=w.w*hv;
      }
      float* dst=p3+(size_t)l*32768+(size_t)(cg*8+bs+bi)*256+4*chunk;
      ast(dst+0,ax);ast(dst+1,ay);ast(dst+2,az);ast(dst+3,aw);
    }
    __syncthreads();
    if(tid<4) asti(F3+((l*8+bs+tid)*16+cg)*32,t+1);
  }
}

// ========================= HEAD: per-b full head ===========================
DEV void role_head(float* LDS,int b,
    const float* __restrict__ op_w1,const float* __restrict__ op_b1,
    const float* __restrict__ bn_g,const float* __restrict__ bn_b,
    const float* __restrict__ op_w2,const float* __restrict__ op_b2,
    const float* __restrict__ emb_w,
    const float* __restrict__ ln2_g,const float* __restrict__ ln2_b,
    const float* __restrict__ ln3_g,const float* __restrict__ ln3_b,
    const float* __restrict__ ffn_b2,
    const int* F3,int* FX0,
    const float* r2red,const float* p3,float* xrow,float* outp){
  const int tid=threadIdx.x;
  float* X  =LDS;           // 256
  float* Y  =LDS+256;       // 256
  float* LG =LDS+512;       // 128
  float* RED=LDS+768;       // 16

  for(int t=0;t<64;++t){
    waitflags(F3+(8+b)*16*32,16,t+1);     // layer-1 S3 flags for this b
    const int c=tid;
    X[c]=ald(r2red+2048+b*256+c);
    lnR(X,1,ln2_g+256,ln2_b+256,RED);
    {
      float s=0.f;
#pragma unroll
      for(int cg=0;cg<16;++cg) s+=ald(p3+32768+(cg*8+b)*256+c);
      X[c]+=s+ffn_b2[256+c];
    }
    lnR(X,1,ln3_g+256,ln3_b+256,RED);
    // y = X @ op_w1.T + b1, bn affine + relu.  K-split 16, coalesced.
    {
      int g=tid&15,cc=tid>>4;
      for(int it=0;it<16;++it){
        int c2=it*16+cc;
        const float4* w4=(const float4*)(op_w1+(size_t)c2*256+g*16);
        const float4* x4=(const float4*)(X+g*16);
        float a=0.f;
#pragma unroll
        for(int i=0;i<4;++i) a+=D4(w4[i],x4[i]);
        a+=__shfl_down(a,8,64);a+=__shfl_down(a,4,64);
        a+=__shfl_down(a,2,64);a+=__shfl_down(a,1,64);
        if(g==0){
          float y=a+op_b1[c2];
          Y[c2]=fmaxf(y*BNS*bn_g[c2]+bn_b[c2],0.f);
        }
      }
    }
    __syncthreads();
    // logits = Y @ op_w2.T + b2 (128 cols), write out. K-split 16.
    {
      int g=tid&15,cc=tid>>4;
      for(int it=0;it<8;++it){
        int c2=it*16+cc;
        const float4* w4=(const float4*)(op_w2+(size_t)c2*256+g*16);
        const float4* y4=(const float4*)(Y+g*16);
        float a=0.f;
#pragma unroll
        for(int i=0;i<4;++i) a+=D4(w4[i],y4[i]);
        a+=__shfl_down(a,8,64);a+=__shfl_down(a,4,64);
        a+=__shfl_down(a,2,64);a+=__shfl_down(a,1,64);
        if(g==0){
          float v=a+op_b2[c2];
          LG[c2]=v;
          outp[((size_t)b*64+t)*128+c2]=v;
        }
      }
    }
    __syncthreads();
    // xrow[b][c] = LG . emb_w[c,:]  (K=128, K-split 8, coalesced)
    if(t<63){
      int g=tid&7,cc=tid>>3;
      for(int it=0;it<8;++it){
        int c2=it*32+cc;
        const float4* w4=(const float4*)(emb_w+(size_t)c2*128+g*16);
        const float4* l4=(const float4*)(LG+g*16);
        float a=0.f;
#pragma unroll
        for(int i=0;i<4;++i) a+=D4(w4[i],l4[i]);
        a+=__shfl_down(a,4,64);a+=__shfl_down(a,2,64);a+=__shfl_down(a,1,64);
        if(g==0) ast(xrow+b*256+c2,a);
      }
    }
    __syncthreads();
    if(tid==0) asti(FX0+b*32,t+1);
  }
}

// ---------------------------------------------------------------------------

__global__ void __launch_bounds__(256,1) k_decode(
    const float* enc,const float* emb_w,const float* emb_b,
    const float* sa_wqkv,const float* sa_bqkv,const float* sa_wo,const float* sa_bo,
    const float* ca_wqkv,const float* ca_bqkv,const float* ca_wo,const float* ca_bo,
    const float* ln1_g,const float* ln1_b,const float* ln2_g,const float* ln2_b,
    const float* ffn_w1,const float* ffn_b1,const float* ffn_w2,const float* ffn_b2,
    const float* ln3_g,const float* ln3_b,
    const float* op_w1,const float* op_b1,const float* bn_g,const float* bn_b,
    const float* op_w2,const float* op_b2,
    int* FX0,int* F1,int* F2,int* F3,
    float* xrow,float* kc,float* vc,float* r1red,float* r2red,float* r3red,
    float* p1,float* p2,float* p3,float* outp){
  __shared__ __align__(16) float LDS[DYNF];
  const int blk=blockIdx.x;
  if(blk<32){
    role_s1(LDS,blk,sa_wqkv,sa_bqkv,sa_wo,ln2_g,ln2_b,ln3_g,ln3_b,ffn_b2,emb_b,
            F1,F3,FX0,kc,vc,r2red,r3red,p3,p1,xrow);
  }else if(blk<160){
    role_s2(LDS,blk-32,enc,ca_wqkv,ca_bqkv,ca_wo,ln1_g,ln1_b,ln3_g,ln3_b,sa_bo,emb_b,
            F1,F2,r3red,r1red,p1,p2,xrow);
  }else if(blk<224){
    role_s3(LDS,blk-160,ffn_w1,ffn_b1,ffn_w2,ln1_g,ln1_b,ln2_g,ln2_b,ca_bo,
            F2,F3,r1red,r2red,p2,p3);
  }else{
    role_head(LDS,blk-224,op_w1,op_b1,bn_g,bn_b,op_w2,op_b2,emb_w,
              ln2_g,ln2_b,ln3_g,ln3_b,ffn_b2,F3,FX0,r2red,p3,xrow,outp);
  }
}

// ---------------------------------------------------------------------------

extern "C" void kernel_launch(void* const* d_in, const int* in_sizes, int n_in,
                              void* d_out, int out_size, void* d_ws, size_t ws_size,
                              hipStream_t stream) {
  (void)in_sizes;(void)n_in;(void)out_size;(void)ws_size;
  const float* enc     =(const float*)d_in[0];
  const float* emb_w   =(const float*)d_in[1];
  const float* emb_b   =(const float*)d_in[2];
  const float* sa_wqkv =(const float*)d_in[3];
  const float* sa_bqkv =(const float*)d_in[4];
  const float* sa_wo   =(const float*)d_in[5];
  const float* sa_bo   =(const float*)d_in[6];
  const float* ca_wqkv =(const float*)d_in[7];
  const float* ca_bqkv =(const float*)d_in[8];
  const float* ca_wo   =(const float*)d_in[9];
  const float* ca_bo   =(const float*)d_in[10];
  const float* ln1_g   =(const float*)d_in[11];
  const float* ln1_b   =(const float*)d_in[12];
  const float* ln2_g   =(const float*)d_in[13];
  const float* ln2_b   =(const float*)d_in[14];
  const float* ffn_w1  =(const float*)d_in[15];
  const float* ffn_b1  =(const float*)d_in[16];
  const float* ffn_w2  =(const float*)d_in[17];
  const float* ffn_b2  =(const float*)d_in[18];
  const float* ln3_g   =(const float*)d_in[19];
  const float* ln3_b   =(const float*)d_in[20];
  const float* op_w1   =(const float*)d_in[21];
  const float* op_b1   =(const float*)d_in[22];
  const float* bn_g    =(const float*)d_in[23];
  const float* bn_b    =(const float*)d_in[24];
  const float* op_w2   =(const float*)d_in[25];
  const float* op_b2   =(const float*)d_in[26];

  float* out=(float*)d_out;

  // Flags: one per 128B line (stride 32 ints).
  //   FX0: 8 slots, F1: 128, F2: 128, F3: 256  -> 16640 ints total.
  int* I=(int*)d_ws;
  int* FX0=I;                // [0,256)
  int* F1 =I+256;            // 128 slots * 32
  int* F2 =I+4352;           // 128 slots * 32
  int* F3 =I+8448;           // 256 slots * 32  -> end 16640
  // zero flags + xrow each call (graph-captured)
  hipMemsetAsync(d_ws,0,16640*4+2048*4,stream);

  float* F=(float*)d_ws+16640;
  float* xrow =F;               // 8 x 256
  float* kc   =xrow+2048;       // 2 x 8 x 8 x 64 x 32
  float* vc   =kc+262144;
  float* r1red=vc+262144;       // 2 x 8 x 256
  float* r2red=r1red+4096;      // 2 x 8 x 256
  float* r3red=r2red+4096;      // 8 x 256
  float* p1   =r3red+2048;      // 8h x 8b x 256
  float* p2   =p1+16384;        // 8h x 8b x 256
  float* p3   =p2+16384;        // 2 x 16 x 8 x 256

  k_decode<<<232,256,0,stream>>>(
      enc,emb_w,emb_b,sa_wqkv,sa_bqkv,sa_wo,sa_bo,
      ca_wqkv,ca_bqkv,ca_wo,ca_bo,ln1_g,ln1_b,ln2_g,ln2_b,
      ffn_w1,ffn_b1,ffn_w2,ffn_b2,ln3_g,ln3_b,
      op_w1,op_b1,bn_g,bn_b,op_w2,op_b2,
      FX0,F1,F2,F3,
      xrow,kc,vc,r1red,r2red,r3red,p1,p2,p3,out);
}

// Round 9
// 3806.242 us; speedup vs baseline: 1.8011x; 1.2627x over previous
//
#include <hip/hip_runtime.h>
#include <math.h>

// ---------------------------------------------------------------------------
// TransformerDecoder: weight-stationary persistent dataflow decode, v3.
// B=8, S_SRC=256, T=64, D=256, H=8, HD=32, DFF=1024, NC=128, L=2. fp32.
// 248 blocks (1/CU, <=147KB LDS):
//   S1L0 [0,16):  (h,bhalf)    4b each, SA layer0
//   S1L1 [16,48): (h,bpair)    2b each, SA layer1 (+r3 assembly)
//   S2  [48,176): (b,h,l)      p1-reduce, CA (memKV in LDS), proj partial
//   S3 [176,240): (l,cg16,bh)  p2-reduce, FFN1 + FFN2 partial
//   HEAD[240,248):(b)          r3(l1), op_w1+BN+relu, logits, out, emb->xrow
// v3: reg-hoisted MALL loads above LN, 1-barrier ln_reg, parallel qc,
// pure-spin padded-flag polls.
// ---------------------------------------------------------------------------

#define EPS_ 1e-5f
#define SCALE_ 0.17677669529663687f   // 1/sqrt(32)
#define BNS 0.99999500003749969f      // 1/sqrt(1+1e-5)
#define DEV __device__ __forceinline__
#define DYNF 36864                     // LDS floats per block (147456 B)

#define D4(a,b) ((a).x*(b).x+(a).y*(b).y+(a).z*(b).z+(a).w*(b).w)
#define F4(p)  (*(float4*)(p))
#define CF4(p) (*(const float4*)(p))

DEV float ald(const float* p){return __hip_atomic_load(p,__ATOMIC_RELAXED,__HIP_MEMORY_SCOPE_AGENT);}
DEV void  ast(float* p,float v){__hip_atomic_store(p,v,__ATOMIC_RELAXED,__HIP_MEMORY_SCOPE_AGENT);}
DEV int   aldi(const int* p){return __hip_atomic_load(p,__ATOMIC_RELAXED,__HIP_MEMORY_SCOPE_AGENT);}
DEV void  asti(int* p,int v){__hip_atomic_store(p,v,__ATOMIC_RELAXED,__HIP_MEMORY_SCOPE_AGENT);}

DEV float wsum(float v){
#pragma unroll
  for(int o=32;o;o>>=1) v+=__shfl_xor(v,o,64);
  return v;
}
DEV float wmax(float v){
#pragma unroll
  for(int o=32;o;o>>=1) v=fmaxf(v,__shfl_xor(v,o,64));
  return v;
}

// wave-0 polls n (<=64) flags, each on its own 128B line; pure spin.
DEV void waitflags(const int* base,int n,int s){
  if((int)threadIdx.x<64){
    const int* p=base+threadIdx.x*32;
    bool need=(int)threadIdx.x<n;
    int v=need?aldi(p):0x7fffffff;
    while(!__all(v>=s)){ v=need?aldi(p):0x7fffffff; }
  }
  __syncthreads();
}

// LayerNorm of NB register values (column tid of each row). 1 barrier.
// red needs NB*8 floats; alternate offsets between back-to-back calls.
template<int NB>
DEV void ln_reg(float (&v)[NB],const float* __restrict__ g,
                const float* __restrict__ bb,float* red){
  int tid=threadIdx.x,wid=tid>>6,lane=tid&63;
  float s[NB],s2[NB];
#pragma unroll
  for(int r=0;r<NB;++r){ s[r]=wsum(v[r]); s2[r]=wsum(v[r]*v[r]); }
  if(lane==0){
#pragma unroll
    for(int r=0;r<NB;++r){ red[r*4+wid]=s[r]; red[NB*4+r*4+wid]=s2[r]; }
  }
  __syncthreads();
  float gv=g[tid],bv=bb[tid];
#pragma unroll
  for(int r=0;r<NB;++r){
    float S=red[r*4+0]+red[r*4+1]+red[r*4+2]+red[r*4+3];
    float S2=red[NB*4+r*4+0]+red[NB*4+r*4+1]+red[NB*4+r*4+2]+red[NB*4+r*4+3];
    float m=S*(1.f/256.f);
    float rs=rsqrtf(S2*(1.f/256.f)-m*m+EPS_);
    v[r]=(v[r]-m)*rs*gv+bv;
  }
}

// ============================ S1: self-attention ============================
template<int NB,int L>
DEV void role_s1(float* LDS,int h,int bs,
    const float* __restrict__ sa_wqkv,const float* __restrict__ sa_bqkv,
    const float* __restrict__ sa_wo,
    const float* __restrict__ ln2_g,const float* __restrict__ ln2_b,
    const float* __restrict__ ln3_g,const float* __restrict__ ln3_b,
    const float* __restrict__ ffn_b2,const float* __restrict__ emb_b,
    int* F1,const int* F3,const int* FX0,
    float* kc,float* vc,const float* r2red,float* r3red,
    const float* p3,float* p1,const float* xrow){
  const int tid=threadIdx.x;
  float* W   =LDS;          // 96 x 260
  float* WO  =LDS+24960;    // 256 x 36
  float* XS  =LDS+34176;    // NB x 256
  float* QKV =LDS+35200;    // NB x 96
  float* SC  =LDS+35584;    // NB x 64
  float* PART=LDS+35840;    // NB x 64
  float* RED =LDS+36096;    // 64

  for(int idx=tid;idx<96*64;idx+=256){
    int row=idx>>6,i4=idx&63,which=row>>5,j=row&31;
    F4(&W[row*260+4*i4])=CF4(sa_wqkv+(size_t)L*196608+((size_t)(which*256+h*32+j))*256+4*i4);
  }
  for(int idx=tid;idx<256*8;idx+=256){
    int c=idx>>3,i=idx&7;
    F4(&WO[c*36+4*i])=CF4(sa_wo+(size_t)L*65536+(size_t)c*256+h*32+4*i);
  }
  __syncthreads();

  float dv=expf((float)(tid&~1)*(-9.210340371976184f/256.f));

  for(int t=0;t<64;++t){
    if(L==0){
      waitflags(FX0+bs*32,NB,t);
      float aarg=(float)t*dv;
      float peb=emb_b[tid]+((tid&1)?cosf(aarg):sinf(aarg));
#pragma unroll
      for(int bi=0;bi<NB;++bi) XS[bi*256+tid]=ald(xrow+(bs+bi)*256+tid)+peb;
      __syncthreads();
    }else{
      waitflags(F3+bs*16*32,NB*16,t+1);   // layer-0 S3 flags for our b's
      float r2v[NB],p3v[NB][16];
#pragma unroll
      for(int bi=0;bi<NB;++bi) r2v[bi]=ald(r2red+(bs+bi)*256+tid);
#pragma unroll
      for(int bi=0;bi<NB;++bi)
#pragma unroll
        for(int cg=0;cg<16;++cg) p3v[bi][cg]=ald(p3+(cg*8+bs+bi)*256+tid);
      ln_reg<NB>(r2v,ln2_g,ln2_b,RED);       // LN2(l0); overlaps p3 latency
      float r3v[NB];
      float fb=ffn_b2[tid];
#pragma unroll
      for(int bi=0;bi<NB;++bi){
        float s=0.f;
#pragma unroll
        for(int cg=0;cg<16;++cg) s+=p3v[bi][cg];
        r3v[bi]=r2v[bi]+s+fb;
        if(h==0) ast(r3red+(bs+bi)*256+tid,r3v[bi]);
      }
      ln_reg<NB>(r3v,ln3_g,ln3_b,RED+32);    // LN3(l0)
#pragma unroll
      for(int bi=0;bi<NB;++bi) XS[bi*256+tid]=r3v[bi];
      __syncthreads();
    }
    // qkv for current token (96 rows x NB b, K-split 2)
    if(tid<192){
      int row=tid>>1,kq=tid&1;
      float a[NB];
#pragma unroll
      for(int bi=0;bi<NB;++bi) a[bi]=0.f;
#pragma unroll
      for(int i=0;i<32;++i){
        float4 w=F4(&W[row*260+kq*128+4*i]);
#pragma unroll
        for(int bi=0;bi<NB;++bi) a[bi]+=D4(w,F4(&XS[bi*256+kq*128+4*i]));
      }
#pragma unroll
      for(int bi=0;bi<NB;++bi) a[bi]+=__shfl_down(a[bi],1,64);
      if(kq==0){
        int which=row>>5,j=row&31;
        float bias=sa_bqkv[L*768+which*256+h*32+j];
#pragma unroll
        for(int bi=0;bi<NB;++bi){
          float v=a[bi]+bias;
          if(which==0) QKV[bi*96+j]=v;
          else{
            int off=(which==1)?32:64;
            QKV[bi*96+off+j]=v;
            float* cache=(which==1)?kc:vc;
            cache[(((size_t)L*64+(bs+bi)*8+h)*64+t)*32+j]=v;
          }
        }
      }
    }
    __syncthreads();
    // causal scores: wave->b  (duplicated waves for NB=2 are benign)
    {
      int bi=(tid>>6)&(NB-1),key=tid&63;
      float s=-3.0e38f;
      if(key<=t){
        float a=0.f;
        if(key==t){
#pragma unroll
          for(int i=0;i<8;++i) a+=D4(F4(&QKV[bi*96+4*i]),F4(&QKV[bi*96+32+4*i]));
        }else{
          const float4* kr=(const float4*)(kc+(((size_t)L*64+(bs+bi)*8+h)*64+key)*32);
#pragma unroll
          for(int i=0;i<8;++i) a+=D4(F4(&QKV[bi*96+4*i]),kr[i]);
        }
        s=a*SCALE_;
      }
      float mx=wmax(s);
      float e=(key<=t)?expf(s-mx):0.f;
      float sm=wsum(e);
      SC[bi*64+key]=e/sm;
    }
    __syncthreads();
    // PV
    {
      int bi=(tid>>6)&(NB-1),lane=tid&63,gg=lane>>5,col=lane&31;
      float acc=0.f;
      int k0=gg*32,k1=min(k0+32,t+1);
      for(int k=k0;k<k1;++k){
        float vv=(k==t)?QKV[bi*96+64+col]
                       :vc[(((size_t)L*64+(bs+bi)*8+h)*64+k)*32+col];
        acc+=SC[bi*64+k]*vv;
      }
      PART[bi*64+gg*32+col]=acc;
    }
    __syncthreads();
    if(tid<NB*32){
      int bi=tid>>5,col=tid&31;
      QKV[bi*96+col]=PART[bi*64+col]+PART[bi*64+32+col];  // o_h
    }
    __syncthreads();
    // out-proj partial
    {
      float a[NB];
#pragma unroll
      for(int bi=0;bi<NB;++bi) a[bi]=0.f;
#pragma unroll
      for(int i=0;i<8;++i){
        float4 w=F4(&WO[tid*36+4*i]);
#pragma unroll
        for(int bi=0;bi<NB;++bi) a[bi]+=D4(w,F4(&QKV[bi*96+4*i]));
      }
#pragma unroll
      for(int bi=0;bi<NB;++bi) ast(p1+(h*8+bs+bi)*256+tid,a[bi]);
    }
    __syncthreads();   // drain stores before flags
    if(tid<NB) asti(F1+((L*8+bs+tid)*8+h)*32,t+1);
  }
}

// ============================ S2: cross-attention ===========================
DEV void role_s2(float* LDS,int rid,
    const float* __restrict__ enc,
    const float* __restrict__ ca_wqkv,const float* __restrict__ ca_bqkv,
    const float* __restrict__ ca_wo,
    const float* __restrict__ ln1_g,const float* __restrict__ ln1_b,
    const float* __restrict__ ln3_g,const float* __restrict__ ln3_b,
    const float* __restrict__ sa_bo,const float* __restrict__ emb_b,
    const int* F1,int* F2,
    const float* r3red,float* r1red,const float* p1,float* p2,const float* xrow){
  const int tid=threadIdx.x;
  const int b=rid>>4,h=(rid>>1)&7,l=rid&1;
  float* WQ  =LDS;          // 32 x 260
  float* WO  =LDS+8320;     // 256 x 36
  float* MK  =LDS+17536;    // 256 x 36
  float* MV  =LDS+26752;    // 256 x 36
  float* XS  =LDS+35968;    // 256
  float* PS  =LDS+36224;    // 256
  float* PART=LDS+36480;    // 256
  float* QC  =LDS+36736;    // 48
  float* RED =LDS+36784;    // 64 (ends 36848)

  // prologue (a): temp-load 64 K/V weight rows
  for(int idx=tid;idx<64*64;idx+=256){
    int row=idx>>6,i4=idx&63;
    int grow=(row<32)?(256+h*32+row):(512+h*32+row-32);
    F4(&LDS[row*260+4*i4])=CF4(ca_wqkv+(size_t)l*196608+(size_t)grow*256+4*i4);
  }
  __syncthreads();
  // (b): compute mem K/V slice into LDS
  for(int p=0;p<2;++p){
    int s=p*128+(tid>>1),kh=tid&1;
    float4 er[32];
#pragma unroll
    for(int i=0;i<32;++i) er[i]=CF4(enc+((size_t)(b*256+s))*256+kh*128+4*i);
    for(int out=0;out<64;++out){
      float a=0.f;
#pragma unroll
      for(int i=0;i<32;++i) a+=D4(F4(&LDS[out*260+kh*128+4*i]),er[i]);
      a+=__shfl_down(a,1,64);
      if(kh==0){
        if(out<32) MK[s*36+out]    =a+ca_bqkv[l*768+256+h*32+out];
        else       MV[s*36+out-32] =a+ca_bqkv[l*768+512+h*32+out-32];
      }
    }
  }
  __syncthreads();
  // (c): stationary weights
  for(int idx=tid;idx<32*64;idx+=256){
    int row=idx>>6,i4=idx&63;
    F4(&WQ[row*260+4*i4])=CF4(ca_wqkv+(size_t)l*196608+(size_t)(h*32+row)*256+4*i4);
  }
  for(int idx=tid;idx<256*8;idx+=256){
    int c=idx>>3,i=idx&7;
    F4(&WO[c*36+4*i])=CF4(ca_wo+(size_t)l*65536+(size_t)c*256+h*32+4*i);
  }
  __syncthreads();

  float dv=expf((float)(tid&~1)*(-9.210340371976184f/256.f));

  for(int t=0;t<64;++t){
    waitflags(F1+(l*8+b)*8*32,8,t+1);
    float p1v[8];
#pragma unroll
    for(int h2=0;h2<8;++h2) p1v[h2]=ald(p1+(h2*8+b)*256+tid);
    float xv;
    if(l==0){
      float aarg=(float)t*dv;
      xv=ald(xrow+b*256+tid)+emb_b[tid]+((tid&1)?cosf(aarg):sinf(aarg));
    }else{
      float t0[1]={ald(r3red+b*256+tid)};
      ln_reg<1>(t0,ln3_g,ln3_b,RED);        // LN3 (layer0)
      xv=t0[0];
    }
    float r1v=xv+sa_bo[l*256+tid];
#pragma unroll
    for(int h2=0;h2<8;++h2) r1v+=p1v[h2];
    if(h==0) ast(r1red+l*2048+b*256+tid,r1v);
    float t1[1]={r1v};
    ln_reg<1>(t1,ln1_g+l*256,ln1_b+l*256,RED+32);
    XS[tid]=t1[0];
    __syncthreads();
    // qc: 8 lanes per col, all 256 threads
    {
      int col=tid>>3,g=tid&7;
      float a=0.f;
#pragma unroll
      for(int i=0;i<8;++i) a+=D4(F4(&WQ[col*260+g*32+4*i]),F4(&XS[g*32+4*i]));
      a+=__shfl_down(a,4,64);a+=__shfl_down(a,2,64);a+=__shfl_down(a,1,64);
      if(g==0) QC[col]=a+ca_bqkv[l*768+h*32+col];
    }
    __syncthreads();
    // scores over 256 memory positions
    {
      float a=0.f;
#pragma unroll
      for(int i=0;i<8;++i) a+=D4(F4(&MK[tid*36+4*i]),F4(&QC[4*i]));
      float sv=a*SCALE_;
      int wid=tid>>6,lane=tid&63;
      float mx=wmax(sv);
      if(lane==0) RED[wid]=mx;
      __syncthreads();
      mx=fmaxf(fmaxf(RED[0],RED[1]),fmaxf(RED[2],RED[3]));
      float e=expf(sv-mx);
      float sm=wsum(e);
      if(lane==0) RED[4+wid]=sm;
      __syncthreads();
      sm=RED[4]+RED[5]+RED[6]+RED[7];
      PS[tid]=e/sm;
    }
    __syncthreads();
    {
      int gg=tid>>5,col=tid&31;
      float acc=0.f;
      for(int s2=gg*32;s2<gg*32+32;++s2) acc+=PS[s2]*MV[s2*36+col];
      PART[gg*32+col]=acc;
    }
    __syncthreads();
    if(tid<32){
      float o=0.f;
#pragma unroll
      for(int g2=0;g2<8;++g2) o+=PART[g2*32+tid];
      QC[tid]=o;
    }
    __syncthreads();
    {
      float a=0.f;
#pragma unroll
      for(int i=0;i<8;++i) a+=D4(F4(&WO[tid*36+4*i]),F4(&QC[4*i]));
      ast(p2+(h*8+b)*256+tid,a);
    }
    __syncthreads();
    if(tid==0) asti(F2+((l*8+b)*8+h)*32,t+1);
  }
}

// ================================ S3: FFN ==================================
DEV void role_s3(float* LDS,int rid,
    const float* __restrict__ ffn_w1,const float* __restrict__ ffn_b1,
    const float* __restrict__ ffn_w2,
    const float* __restrict__ ln1_g,const float* __restrict__ ln1_b,
    const float* __restrict__ ln2_g,const float* __restrict__ ln2_b,
    const float* __restrict__ ca_bo,
    const int* F2,int* F3,
    const float* r1red,float* r2red,const float* p2,float* p3){
  const int tid=threadIdx.x;
  const int l=rid>>5,cg=(rid>>1)&15,bh=rid&1,bs=bh*4;
  float* W1 =LDS;           // 64 x 260
  float* W2T=LDS+16640;     // 64 x 260 (transposed: [k][c])
  float* X4 =LDS+33280;     // 4 x 256
  float* HH =LDS+34304;     // 4 x 68
  float* RED=LDS+34576;     // 64

  for(int idx=tid;idx<64*64;idx+=256){
    int row=idx>>6,i4=idx&63;
    F4(&W1[row*260+4*i4])=CF4(ffn_w1+(size_t)l*262144+(size_t)(cg*64+row)*256+4*i4);
  }
  for(int idx=tid;idx<256*16;idx+=256){
    int cc=idx>>4,k4=idx&15;
    float4 w=CF4(ffn_w2+(size_t)l*262144+(size_t)cc*1024+cg*64+4*k4);
    W2T[(4*k4+0)*260+cc]=w.x;W2T[(4*k4+1)*260+cc]=w.y;
    W2T[(4*k4+2)*260+cc]=w.z;W2T[(4*k4+3)*260+cc]=w.w;
  }
  __syncthreads();

  for(int t=0;t<64;++t){
    waitflags(F2+(l*8+bs)*8*32,32,t+1);   // 4 b x 8 h
    float r1v[4],p2v[4][8];
#pragma unroll
    for(int bi=0;bi<4;++bi) r1v[bi]=ald(r1red+l*2048+(bs+bi)*256+tid);
#pragma unroll
    for(int bi=0;bi<4;++bi)
#pragma unroll
      for(int h2=0;h2<8;++h2) p2v[bi][h2]=ald(p2+(h2*8+bs+bi)*256+tid);
    ln_reg<4>(r1v,ln1_g+l*256,ln1_b+l*256,RED);   // overlaps p2 latency
    float r2v[4];
    float cb=ca_bo[l*256+tid];
#pragma unroll
    for(int bi=0;bi<4;++bi){
      float s=0.f;
#pragma unroll
      for(int h2=0;h2<8;++h2) s+=p2v[bi][h2];
      r2v[bi]=r1v[bi]+s+cb;
      if(cg==0) ast(r2red+l*2048+(bs+bi)*256+tid,r2v[bi]);
    }
    ln_reg<4>(r2v,ln2_g+l*256,ln2_b+l*256,RED+32);
#pragma unroll
    for(int bi=0;bi<4;++bi) X4[bi*256+tid]=r2v[bi];
    __syncthreads();
    // FFN1: 64 rows x 4 b, K-split 4
    {
      int row=tid>>2,kq=tid&3;
      float a0=0.f,a1=0.f,a2=0.f,a3=0.f;
#pragma unroll
      for(int i=0;i<16;++i){
        float4 w=F4(&W1[row*260+kq*64+4*i]);
        a0+=D4(w,F4(&X4[0*256+kq*64+4*i]));a1+=D4(w,F4(&X4[1*256+kq*64+4*i]));
        a2+=D4(w,F4(&X4[2*256+kq*64+4*i]));a3+=D4(w,F4(&X4[3*256+kq*64+4*i]));
      }
      a0+=__shfl_down(a0,2,64);a0+=__shfl_down(a0,1,64);
      a1+=__shfl_down(a1,2,64);a1+=__shfl_down(a1,1,64);
      a2+=__shfl_down(a2,2,64);a2+=__shfl_down(a2,1,64);
      a3+=__shfl_down(a3,2,64);a3+=__shfl_down(a3,1,64);
      if(kq==0){
        float b1v=ffn_b1[l*1024+cg*64+row];
        HH[0*68+row]=fmaxf(a0+b1v,0.f);HH[1*68+row]=fmaxf(a1+b1v,0.f);
        HH[2*68+row]=fmaxf(a2+b1v,0.f);HH[3*68+row]=fmaxf(a3+b1v,0.f);
      }
    }
    __syncthreads();
    // FFN2 partial over this 64-wide k-slice, all 256 out cols
    {
      int chunk=tid&63,bi=tid>>6;
      float ax=0.f,ay=0.f,az=0.f,aw=0.f;
      for(int k=0;k<64;++k){
        float4 w=F4(&W2T[k*260+4*chunk]);
        float hv=HH[bi*68+k];
        ax+=w.x*hv;ay+=w.y*hv;az+=w.z*hv;aw+=w.w*hv;
      }
      float* dst=p3+(size_t)l*32768+(size_t)(cg*8+bs+bi)*256+4*chunk;
      ast(dst+0,ax);ast(dst+1,ay);ast(dst+2,az);ast(dst+3,aw);
    }
    __syncthreads();
    if(tid<4) asti(F3+((l*8+bs+tid)*16+cg)*32,t+1);
  }
}

// ========================= HEAD: per-b full head ===========================
DEV void role_head(float* LDS,int b,
    const float* __restrict__ op_w1,const float* __restrict__ op_b1,
    const float* __restrict__ bn_g,const float* __restrict__ bn_b,
    const float* __restrict__ op_w2,const float* __restrict__ op_b2,
    const float* __restrict__ emb_w,
    const float* __restrict__ ln2_g,const float* __restrict__ ln2_b,
    const float* __restrict__ ln3_g,const float* __restrict__ ln3_b,
    const float* __restrict__ ffn_b2,
    const int* F3,int* FX0,
    const float* r2red,const float* p3,float* xrow,float* outp){
  const int tid=threadIdx.x;
  float* X  =LDS;           // 256
  float* Y  =LDS+256;       // 256
  float* LG =LDS+512;       // 128
  float* RED=LDS+768;       // 64

  for(int t=0;t<64;++t){
    waitflags(F3+(8+b)*16*32,16,t+1);     // layer-1 S3 flags for this b
    float t0[1]={ald(r2red+2048+b*256+tid)};
    float p3v[16];
#pragma unroll
    for(int cg=0;cg<16;++cg) p3v[cg]=ald(p3+32768+(cg*8+b)*256+tid);
    ln_reg<1>(t0,ln2_g+256,ln2_b+256,RED);
    float r3=t0[0]+ffn_b2[256+tid];
#pragma unroll
    for(int cg=0;cg<16;++cg) r3+=p3v[cg];
    float t1[1]={r3};
    ln_reg<1>(t1,ln3_g+256,ln3_b+256,RED+32);
    X[tid]=t1[0];
    __syncthreads();
    // y = X @ op_w1.T + b1, bn affine + relu.  K-split 16.
    {
      int g=tid&15,cc=tid>>4;
      for(int it=0;it<16;++it){
        int c2=it*16+cc;
        const float4* w4=(const float4*)(op_w1+(size_t)c2*256+g*16);
        const float4* x4=(const float4*)(X+g*16);
        float a=0.f;
#pragma unroll
        for(int i=0;i<4;++i) a+=D4(w4[i],x4[i]);
        a+=__shfl_down(a,8,64);a+=__shfl_down(a,4,64);
        a+=__shfl_down(a,2,64);a+=__shfl_down(a,1,64);
        if(g==0){
          float y=a+op_b1[c2];
          Y[c2]=fmaxf(y*BNS*bn_g[c2]+bn_b[c2],0.f);
        }
      }
    }
    __syncthreads();
    // logits = Y @ op_w2.T + b2 (128 cols), write out. K-split 16.
    {
      int g=tid&15,cc=tid>>4;
      for(int it=0;it<8;++it){
        int c2=it*16+cc;
        const float4* w4=(const float4*)(op_w2+(size_t)c2*256+g*16);
        const float4* y4=(const float4*)(Y+g*16);
        float a=0.f;
#pragma unroll
        for(int i=0;i<4;++i) a+=D4(w4[i],y4[i]);
        a+=__shfl_down(a,8,64);a+=__shfl_down(a,4,64);
        a+=__shfl_down(a,2,64);a+=__shfl_down(a,1,64);
        if(g==0){
          float v=a+op_b2[c2];
          LG[c2]=v;
          outp[((size_t)b*64+t)*128+c2]=v;
        }
      }
    }
    __syncthreads();
    // xrow[b][c] = LG . emb_w[c,:]  (K=128, K-split 8)
    if(t<63){
      int g=tid&7,cc=tid>>3;
      for(int it=0;it<8;++it){
        int c2=it*32+cc;
        const float4* w4=(const float4*)(emb_w+(size_t)c2*128+g*16);
        const float4* l4=(const float4*)(LG+g*16);
        float a=0.f;
#pragma unroll
        for(int i=0;i<4;++i) a+=D4(w4[i],l4[i]);
        a+=__shfl_down(a,4,64);a+=__shfl_down(a,2,64);a+=__shfl_down(a,1,64);
        if(g==0) ast(xrow+b*256+c2,a);
      }
    }
    __syncthreads();
    if(tid==0) asti(FX0+b*32,t+1);
  }
}

// ---------------------------------------------------------------------------

__global__ void __launch_bounds__(256,1) k_decode(
    const float* enc,const float* emb_w,const float* emb_b,
    const float* sa_wqkv,const float* sa_bqkv,const float* sa_wo,const float* sa_bo,
    const float* ca_wqkv,const float* ca_bqkv,const float* ca_wo,const float* ca_bo,
    const float* ln1_g,const float* ln1_b,const float* ln2_g,const float* ln2_b,
    const float* ffn_w1,const float* ffn_b1,const float* ffn_w2,const float* ffn_b2,
    const float* ln3_g,const float* ln3_b,
    const float* op_w1,const float* op_b1,const float* bn_g,const float* bn_b,
    const float* op_w2,const float* op_b2,
    int* FX0,int* F1,int* F2,int* F3,
    float* xrow,float* kc,float* vc,float* r1red,float* r2red,float* r3red,
    float* p1,float* p2,float* p3,float* outp){
  __shared__ __align__(16) float LDS[DYNF];
  const int blk=blockIdx.x;
  if(blk<16){
    role_s1<4,0>(LDS,blk>>1,(blk&1)*4,sa_wqkv,sa_bqkv,sa_wo,ln2_g,ln2_b,ln3_g,ln3_b,
                 ffn_b2,emb_b,F1,F3,FX0,kc,vc,r2red,r3red,p3,p1,xrow);
  }else if(blk<48){
    int r=blk-16;
    role_s1<2,1>(LDS,r>>2,(r&3)*2,sa_wqkv,sa_bqkv,sa_wo,ln2_g,ln2_b,ln3_g,ln3_b,
                 ffn_b2,emb_b,F1,F3,FX0,kc,vc,r2red,r3red,p3,p1,xrow);
  }else if(blk<176){
    role_s2(LDS,blk-48,enc,ca_wqkv,ca_bqkv,ca_wo,ln1_g,ln1_b,ln3_g,ln3_b,sa_bo,emb_b,
            F1,F2,r3red,r1red,p1,p2,xrow);
  }else if(blk<240){
    role_s3(LDS,blk-176,ffn_w1,ffn_b1,ffn_w2,ln1_g,ln1_b,ln2_g,ln2_b,ca_bo,
            F2,F3,r1red,r2red,p2,p3);
  }else{
    role_head(LDS,blk-240,op_w1,op_b1,bn_g,bn_b,op_w2,op_b2,emb_w,
              ln2_g,ln2_b,ln3_g,ln3_b,ffn_b2,F3,FX0,r2red,p3,xrow,outp);
  }
}

// ---------------------------------------------------------------------------

extern "C" void kernel_launch(void* const* d_in, const int* in_sizes, int n_in,
                              void* d_out, int out_size, void* d_ws, size_t ws_size,
                              hipStream_t stream) {
  (void)in_sizes;(void)n_in;(void)out_size;(void)ws_size;
  const float* enc     =(const float*)d_in[0];
  const float* emb_w   =(const float*)d_in[1];
  const float* emb_b   =(const float*)d_in[2];
  const float* sa_wqkv =(const float*)d_in[3];
  const float* sa_bqkv =(const float*)d_in[4];
  const float* sa_wo   =(const float*)d_in[5];
  const float* sa_bo   =(const float*)d_in[6];
  const float* ca_wqkv =(const float*)d_in[7];
  const float* ca_bqkv =(const float*)d_in[8];
  const float* ca_wo   =(const float*)d_in[9];
  const float* ca_bo   =(const float*)d_in[10];
  const float* ln1_g   =(const float*)d_in[11];
  const float* ln1_b   =(const float*)d_in[12];
  const float* ln2_g   =(const float*)d_in[13];
  const float* ln2_b   =(const float*)d_in[14];
  const float* ffn_w1  =(const float*)d_in[15];
  const float* ffn_b1  =(const float*)d_in[16];
  const float* ffn_w2  =(const float*)d_in[17];
  const float* ffn_b2  =(const float*)d_in[18];
  const float* ln3_g   =(const float*)d_in[19];
  const float* ln3_b   =(const float*)d_in[20];
  const float* op_w1   =(const float*)d_in[21];
  const float* op_b1   =(const float*)d_in[22];
  const float* bn_g    =(const float*)d_in[23];
  const float* bn_b    =(const float*)d_in[24];
  const float* op_w2   =(const float*)d_in[25];
  const float* op_b2   =(const float*)d_in[26];

  float* out=(float*)d_out;

  // Flags: one per 128B line (stride 32 ints).
  int* I=(int*)d_ws;
  int* FX0=I;                // 8 slots
  int* F1 =I+256;            // 128 slots
  int* F2 =I+4352;           // 128 slots
  int* F3 =I+8448;           // 256 slots -> end 16640
  hipMemsetAsync(d_ws,0,16640*4+2048*4,stream);

  float* F=(float*)d_ws+16640;
  float* xrow =F;               // 8 x 256
  float* kc   =xrow+2048;       // 2 x 8 x 8 x 64 x 32
  float* vc   =kc+262144;
  float* r1red=vc+262144;       // 2 x 8 x 256
  float* r2red=r1red+4096;      // 2 x 8 x 256
  float* r3red=r2red+4096;      // 8 x 256
  float* p1   =r3red+2048;      // 8h x 8b x 256
  float* p2   =p1+16384;        // 8h x 8b x 256
  float* p3   =p2+16384;        // 2 x 16 x 8 x 256

  k_decode<<<248,256,0,stream>>>(
      enc,emb_w,emb_b,sa_wqkv,sa_bqkv,sa_wo,sa_bo,
      ca_wqkv,ca_bqkv,ca_wo,ca_bo,ln1_g,ln1_b,ln2_g,ln2_b,
      ffn_w1,ffn_b1,ffn_w2,ffn_b2,ln3_g,ln3_b,
      op_w1,op_b1,bn_g,bn_b,op_w2,op_b2,
      FX0,F1,F2,F3,
      xrow,kc,vc,r1red,r2red,r3red,p1,p2,p3,out);
}

// Round 10
// 3606.670 us; speedup vs baseline: 1.9008x; 1.0553x over previous
//
#include <hip/hip_runtime.h>
#include <math.h>

// ---------------------------------------------------------------------------
// TransformerDecoder: weight-stationary persistent dataflow decode, v4.
// B=8, S_SRC=256, T=64, D=256, H=8, HD=32, DFF=1024, NC=128, L=2. fp32.
// 248 blocks (1/CU). v4: split-phase hops — residual rows (r1red/r2red/r3red)
// get EARLY flags (FER*) published right after the reduce, before the
// producer's heavy compute; consumers prefetch + LayerNorm during producer
// compute, leaving only partial-fetch+matmul on the critical path.
//   S1L0 [0,16):  (h,bhalf)   4b, SA layer0
//   S1L1 [16,48): (h,bpair)   2b, SA layer1 (+r3 assembly, FER3)
//   S2  [48,176): (b,h,l)     p1-reduce (FER1), CA, proj partial
//   S3 [176,240): (l,cg16,bh) p2-reduce (FER2), FFN1 + FFN2 partial
//   HEAD[240,248):(b)         r3(l1), op_w1+BN+relu, logits, out, emb->xrow
// ---------------------------------------------------------------------------

#define EPS_ 1e-5f
#define SCALE_ 0.17677669529663687f   // 1/sqrt(32)
#define BNS 0.99999500003749969f      // 1/sqrt(1+1e-5)
#define DEV __device__ __forceinline__
#define DYNF 36864                     // LDS floats per block (147456 B)

#define D4(a,b) ((a).x*(b).x+(a).y*(b).y+(a).z*(b).z+(a).w*(b).w)
#define F4(p)  (*(float4*)(p))
#define CF4(p) (*(const float4*)(p))

DEV float ald(const float* p){return __hip_atomic_load(p,__ATOMIC_RELAXED,__HIP_MEMORY_SCOPE_AGENT);}
DEV void  ast(float* p,float v){__hip_atomic_store(p,v,__ATOMIC_RELAXED,__HIP_MEMORY_SCOPE_AGENT);}
DEV int   aldi(const int* p){return __hip_atomic_load(p,__ATOMIC_RELAXED,__HIP_MEMORY_SCOPE_AGENT);}
DEV void  asti(int* p,int v){__hip_atomic_store(p,v,__ATOMIC_RELAXED,__HIP_MEMORY_SCOPE_AGENT);}

DEV float wsum(float v){
#pragma unroll
  for(int o=32;o;o>>=1) v+=__shfl_xor(v,o,64);
  return v;
}
DEV float wmax(float v){
#pragma unroll
  for(int o=32;o;o>>=1) v=fmaxf(v,__shfl_xor(v,o,64));
  return v;
}

// wave-0 polls n (<=64) flags, each on its own 128B line; pure spin.
DEV void waitflags(const int* base,int n,int s){
  if((int)threadIdx.x<64){
    const int* p=base+threadIdx.x*32;
    bool need=(int)threadIdx.x<n;
    int v=need?aldi(p):0x7fffffff;
    while(!__all(v>=s)){ v=need?aldi(p):0x7fffffff; }
  }
  __syncthreads();
}

// LayerNorm of NB register values (column tid of each row). 1 barrier.
// red needs NB*8 floats; use distinct offsets for back-to-back calls.
template<int NB>
DEV void ln_reg(float (&v)[NB],const float* __restrict__ g,
                const float* __restrict__ bb,float* red){
  int tid=threadIdx.x,wid=tid>>6,lane=tid&63;
  float s[NB],s2[NB];
#pragma unroll
  for(int r=0;r<NB;++r){ s[r]=wsum(v[r]); s2[r]=wsum(v[r]*v[r]); }
  if(lane==0){
#pragma unroll
    for(int r=0;r<NB;++r){ red[r*4+wid]=s[r]; red[NB*4+r*4+wid]=s2[r]; }
  }
  __syncthreads();
  float gv=g[tid],bv=bb[tid];
#pragma unroll
  for(int r=0;r<NB;++r){
    float S=red[r*4+0]+red[r*4+1]+red[r*4+2]+red[r*4+3];
    float S2=red[NB*4+r*4+0]+red[NB*4+r*4+1]+red[NB*4+r*4+2]+red[NB*4+r*4+3];
    float m=S*(1.f/256.f);
    float rs=rsqrtf(S2*(1.f/256.f)-m*m+EPS_);
    v[r]=(v[r]-m)*rs*gv+bv;
  }
}

// ============================ S1: self-attention ============================
template<int NB,int L>
DEV void role_s1(float* LDS,int h,int bs,
    const float* __restrict__ sa_wqkv,const float* __restrict__ sa_bqkv,
    const float* __restrict__ sa_wo,
    const float* __restrict__ ln2_g,const float* __restrict__ ln2_b,
    const float* __restrict__ ln3_g,const float* __restrict__ ln3_b,
    const float* __restrict__ ffn_b2,const float* __restrict__ emb_b,
    int* F1,const int* F3,const int* FX0,const int* FER2,int* FER3,
    float* kc,float* vc,const float* r2red,float* r3red,
    const float* p3,float* p1,const float* xrow){
  const int tid=threadIdx.x;
  float* W   =LDS;          // 96 x 260
  float* WO  =LDS+24960;    // 256 x 36
  float* XS  =LDS+34176;    // NB x 256
  float* QKV =LDS+35200;    // NB x 96
  float* SC  =LDS+35584;    // NB x 64
  float* PART=LDS+35840;    // NB x 64
  float* RED =LDS+36096;    // 64

  for(int idx=tid;idx<96*64;idx+=256){
    int row=idx>>6,i4=idx&63,which=row>>5,j=row&31;
    F4(&W[row*260+4*i4])=CF4(sa_wqkv+(size_t)L*196608+((size_t)(which*256+h*32+j))*256+4*i4);
  }
  for(int idx=tid;idx<256*8;idx+=256){
    int c=idx>>3,i=idx&7;
    F4(&WO[c*36+4*i])=CF4(sa_wo+(size_t)L*65536+(size_t)c*256+h*32+4*i);
  }
  __syncthreads();

  float dv=expf((float)(tid&~1)*(-9.210340371976184f/256.f));

  for(int t=0;t<64;++t){
    if(L==0){
      float aarg=(float)t*dv;
      float peb=emb_b[tid]+((tid&1)?cosf(aarg):sinf(aarg));  // hoisted above wait
      waitflags(FX0+bs*32,NB,t);
#pragma unroll
      for(int bi=0;bi<NB;++bi) XS[bi*256+tid]=ald(xrow+(bs+bi)*256+tid)+peb;
      __syncthreads();
    }else{
      // ---- EARLY: r2red (FER2 l0) + LN2 while S3(l0) does its FFN ----
      waitflags(FER2+bs*32,NB,t+1);
      float r2v[NB];
#pragma unroll
      for(int bi=0;bi<NB;++bi) r2v[bi]=ald(r2red+(bs+bi)*256+tid);
      ln_reg<NB>(r2v,ln2_g,ln2_b,RED);
      // ---- LATE: p3 partials ----
      waitflags(F3+bs*16*32,NB*16,t+1);   // l=0 slots (b,cg)
      float p3v[NB][16];
#pragma unroll
      for(int bi=0;bi<NB;++bi)
#pragma unroll
        for(int cg=0;cg<16;++cg) p3v[bi][cg]=ald(p3+(cg*8+bs+bi)*256+tid);
      float r3v[NB];
      float fb=ffn_b2[tid];
#pragma unroll
      for(int bi=0;bi<NB;++bi){
        float s=0.f;
#pragma unroll
        for(int cg=0;cg<16;++cg) s+=p3v[bi][cg];
        r3v[bi]=r2v[bi]+s+fb;
      }
      if(h==0){
#pragma unroll
        for(int bi=0;bi<NB;++bi) ast(r3red+(bs+bi)*256+tid,r3v[bi]);
        __syncthreads();                      // drain r3red stores
        if(tid<NB) asti(FER3+(bs+tid)*32,t+1);
      }
      ln_reg<NB>(r3v,ln3_g,ln3_b,RED+32);
#pragma unroll
      for(int bi=0;bi<NB;++bi) XS[bi*256+tid]=r3v[bi];
      __syncthreads();
    }
    // qkv for current token (96 rows x NB b, K-split 2)
    if(tid<192){
      int row=tid>>1,kq=tid&1;
      float a[NB];
#pragma unroll
      for(int bi=0;bi<NB;++bi) a[bi]=0.f;
#pragma unroll
      for(int i=0;i<32;++i){
        float4 w=F4(&W[row*260+kq*128+4*i]);
#pragma unroll
        for(int bi=0;bi<NB;++bi) a[bi]+=D4(w,F4(&XS[bi*256+kq*128+4*i]));
      }
#pragma unroll
      for(int bi=0;bi<NB;++bi) a[bi]+=__shfl_down(a[bi],1,64);
      if(kq==0){
        int which=row>>5,j=row&31;
        float bias=sa_bqkv[L*768+which*256+h*32+j];
#pragma unroll
        for(int bi=0;bi<NB;++bi){
          float v=a[bi]+bias;
          if(which==0) QKV[bi*96+j]=v;
          else{
            int off=(which==1)?32:64;
            QKV[bi*96+off+j]=v;
            float* cache=(which==1)?kc:vc;
            cache[(((size_t)L*64+(bs+bi)*8+h)*64+t)*32+j]=v;
          }
        }
      }
    }
    __syncthreads();
    // causal scores: wave->b
    {
      int bi=(tid>>6)&(NB-1),key=tid&63;
      float s=-3.0e38f;
      if(key<=t){
        float a=0.f;
        if(key==t){
#pragma unroll
          for(int i=0;i<8;++i) a+=D4(F4(&QKV[bi*96+4*i]),F4(&QKV[bi*96+32+4*i]));
        }else{
          const float4* kr=(const float4*)(kc+(((size_t)L*64+(bs+bi)*8+h)*64+key)*32);
#pragma unroll
          for(int i=0;i<8;++i) a+=D4(F4(&QKV[bi*96+4*i]),kr[i]);
        }
        s=a*SCALE_;
      }
      float mx=wmax(s);
      float e=(key<=t)?expf(s-mx):0.f;
      float sm=wsum(e);
      SC[bi*64+key]=e/sm;
    }
    __syncthreads();
    // PV
    {
      int bi=(tid>>6)&(NB-1),lane=tid&63,gg=lane>>5,col=lane&31;
      float acc=0.f;
      int k0=gg*32,k1=min(k0+32,t+1);
      for(int k=k0;k<k1;++k){
        float vv=(k==t)?QKV[bi*96+64+col]
                       :vc[(((size_t)L*64+(bs+bi)*8+h)*64+k)*32+col];
        acc+=SC[bi*64+k]*vv;
      }
      PART[bi*64+gg*32+col]=acc;
    }
    __syncthreads();
    if(tid<NB*32){
      int bi=tid>>5,col=tid&31;
      QKV[bi*96+col]=PART[bi*64+col]+PART[bi*64+32+col];  // o_h
    }
    __syncthreads();
    // out-proj partial
    {
      float a[NB];
#pragma unroll
      for(int bi=0;bi<NB;++bi) a[bi]=0.f;
#pragma unroll
      for(int i=0;i<8;++i){
        float4 w=F4(&WO[tid*36+4*i]);
#pragma unroll
        for(int bi=0;bi<NB;++bi) a[bi]+=D4(w,F4(&QKV[bi*96+4*i]));
      }
#pragma unroll
      for(int bi=0;bi<NB;++bi) ast(p1+(h*8+bs+bi)*256+tid,a[bi]);
    }
    __syncthreads();   // drain stores before flags
    if(tid<NB) asti(F1+((L*8+bs+tid)*8+h)*32,t+1);
  }
}

// ============================ S2: cross-attention ===========================
DEV void role_s2(float* LDS,int rid,
    const float* __restrict__ enc,
    const float* __restrict__ ca_wqkv,const float* __restrict__ ca_bqkv,
    const float* __restrict__ ca_wo,
    const float* __restrict__ ln1_g,const float* __restrict__ ln1_b,
    const float* __restrict__ ln3_g,const float* __restrict__ ln3_b,
    const float* __restrict__ sa_bo,const float* __restrict__ emb_b,
    const int* F1,int* F2,const int* FX0,const int* FER3,int* FER1,
    const float* r3red,float* r1red,const float* p1,float* p2,const float* xrow){
  const int tid=threadIdx.x;
  const int b=rid>>4,h=(rid>>1)&7,l=rid&1;
  float* WQ  =LDS;          // 32 x 260
  float* WO  =LDS+8320;     // 256 x 36
  float* MK  =LDS+17536;    // 256 x 36
  float* MV  =LDS+26752;    // 256 x 36
  float* XS  =LDS+35968;    // 256
  float* PS  =LDS+36224;    // 256
  float* PART=LDS+36480;    // 256
  float* QC  =LDS+36736;    // 48
  float* RED =LDS+36784;    // 64

  // prologue (a): temp-load 64 K/V weight rows
  for(int idx=tid;idx<64*64;idx+=256){
    int row=idx>>6,i4=idx&63;
    int grow=(row<32)?(256+h*32+row):(512+h*32+row-32);
    F4(&LDS[row*260+4*i4])=CF4(ca_wqkv+(size_t)l*196608+(size_t)grow*256+4*i4);
  }
  __syncthreads();
  // (b): compute mem K/V slice into LDS
  for(int p=0;p<2;++p){
    int s=p*128+(tid>>1),kh=tid&1;
    float4 er[32];
#pragma unroll
    for(int i=0;i<32;++i) er[i]=CF4(enc+((size_t)(b*256+s))*256+kh*128+4*i);
    for(int out=0;out<64;++out){
      float a=0.f;
#pragma unroll
      for(int i=0;i<32;++i) a+=D4(F4(&LDS[out*260+kh*128+4*i]),er[i]);
      a+=__shfl_down(a,1,64);
      if(kh==0){
        if(out<32) MK[s*36+out]    =a+ca_bqkv[l*768+256+h*32+out];
        else       MV[s*36+out-32] =a+ca_bqkv[l*768+512+h*32+out-32];
      }
    }
  }
  __syncthreads();
  // (c): stationary weights
  for(int idx=tid;idx<32*64;idx+=256){
    int row=idx>>6,i4=idx&63;
    F4(&WQ[row*260+4*i4])=CF4(ca_wqkv+(size_t)l*196608+(size_t)(h*32+row)*256+4*i4);
  }
  for(int idx=tid;idx<256*8;idx+=256){
    int c=idx>>3,i=idx&7;
    F4(&WO[c*36+4*i])=CF4(ca_wo+(size_t)l*65536+(size_t)c*256+h*32+4*i);
  }
  __syncthreads();

  float dv=expf((float)(tid&~1)*(-9.210340371976184f/256.f));

  for(int t=0;t<64;++t){
    // ---- EARLY: residual row + its LN while S1 does SA ----
    float xv;
    if(l==0){
      float aarg=(float)t*dv;
      float peb=emb_b[tid]+((tid&1)?cosf(aarg):sinf(aarg));
      waitflags(FX0+b*32,1,t);
      xv=ald(xrow+b*256+tid)+peb;
    }else{
      waitflags(FER3+b*32,1,t+1);
      float t0[1]={ald(r3red+b*256+tid)};
      ln_reg<1>(t0,ln3_g,ln3_b,RED);        // LN3 (layer0)
      xv=t0[0];
    }
    // ---- LATE: p1 partials ----
    waitflags(F1+(l*8+b)*8*32,8,t+1);
    float p1v[8];
#pragma unroll
    for(int h2=0;h2<8;++h2) p1v[h2]=ald(p1+(h2*8+b)*256+tid);
    float r1v=xv+sa_bo[l*256+tid];
#pragma unroll
    for(int h2=0;h2<8;++h2) r1v+=p1v[h2];
    if(h==0){
      ast(r1red+l*2048+b*256+tid,r1v);
      __syncthreads();                      // drain r1red store
      if(tid==0) asti(FER1+(l*8+b)*32,t+1);
    }
    float t1[1]={r1v};
    ln_reg<1>(t1,ln1_g+l*256,ln1_b+l*256,RED+8);
    XS[tid]=t1[0];
    __syncthreads();
    // qc: 8 lanes per col
    {
      int col=tid>>3,g=tid&7;
      float a=0.f;
#pragma unroll
      for(int i=0;i<8;++i) a+=D4(F4(&WQ[col*260+g*32+4*i]),F4(&XS[g*32+4*i]));
      a+=__shfl_down(a,4,64);a+=__shfl_down(a,2,64);a+=__shfl_down(a,1,64);
      if(g==0) QC[col]=a+ca_bqkv[l*768+h*32+col];
    }
    __syncthreads();
    // scores over 256 memory positions (single-merge softmax: 2 barriers)
    {
      float a=0.f;
#pragma unroll
      for(int i=0;i<8;++i) a+=D4(F4(&MK[tid*36+4*i]),F4(&QC[4*i]));
      float sv=a*SCALE_;
      int wid=tid>>6,lane=tid&63;
      float mw=wmax(sv);
      float e=expf(sv-mw);
      float sw=wsum(e);
      if(lane==0){RED[16+wid]=mw;RED[20+wid]=sw;}
      __syncthreads();
      float M=fmaxf(fmaxf(RED[16],RED[17]),fmaxf(RED[18],RED[19]));
      float tot=RED[20]*expf(RED[16]-M)+RED[21]*expf(RED[17]-M)
               +RED[22]*expf(RED[18]-M)+RED[23]*expf(RED[19]-M);
      PS[tid]=e*expf(mw-M)/tot;
    }
    __syncthreads();
    {
      int gg=tid>>5,col=tid&31;
      float acc=0.f;
      for(int s2=gg*32;s2<gg*32+32;++s2) acc+=PS[s2]*MV[s2*36+col];
      PART[gg*32+col]=acc;
    }
    __syncthreads();
    if(tid<32){
      float o=0.f;
#pragma unroll
      for(int g2=0;g2<8;++g2) o+=PART[g2*32+tid];
      QC[tid]=o;
    }
    __syncthreads();
    {
      float a=0.f;
#pragma unroll
      for(int i=0;i<8;++i) a+=D4(F4(&WO[tid*36+4*i]),F4(&QC[4*i]));
      ast(p2+(h*8+b)*256+tid,a);
    }
    __syncthreads();
    if(tid==0) asti(F2+((l*8+b)*8+h)*32,t+1);
  }
}

// ================================ S3: FFN ==================================
DEV void role_s3(float* LDS,int rid,
    const float* __restrict__ ffn_w1,const float* __restrict__ ffn_b1,
    const float* __restrict__ ffn_w2,
    const float* __restrict__ ln1_g,const float* __restrict__ ln1_b,
    const float* __restrict__ ln2_g,const float* __restrict__ ln2_b,
    const float* __restrict__ ca_bo,
    const int* F2,int* F3,const int* FER1,int* FER2,
    const float* r1red,float* r2red,const float* p2,float* p3){
  const int tid=threadIdx.x;
  const int l=rid>>5,cg=(rid>>1)&15,bh=rid&1,bs=bh*4;
  float* W1 =LDS;           // 64 x 260
  float* W2T=LDS+16640;     // 64 x 260 (transposed: [k][c])
  float* X4 =LDS+33280;     // 4 x 256
  float* HH =LDS+34304;     // 4 x 68
  float* RED=LDS+34576;     // 64

  for(int idx=tid;idx<64*64;idx+=256){
    int row=idx>>6,i4=idx&63;
    F4(&W1[row*260+4*i4])=CF4(ffn_w1+(size_t)l*262144+(size_t)(cg*64+row)*256+4*i4);
  }
  for(int idx=tid;idx<256*16;idx+=256){
    int cc=idx>>4,k4=idx&15;
    float4 w=CF4(ffn_w2+(size_t)l*262144+(size_t)cc*1024+cg*64+4*k4);
    W2T[(4*k4+0)*260+cc]=w.x;W2T[(4*k4+1)*260+cc]=w.y;
    W2T[(4*k4+2)*260+cc]=w.z;W2T[(4*k4+3)*260+cc]=w.w;
  }
  __syncthreads();

  for(int t=0;t<64;++t){
    // ---- EARLY: r1red + LN1 while S2 does CA ----
    waitflags(FER1+(l*8+bs)*32,4,t+1);
    float r1v[4];
#pragma unroll
    for(int bi=0;bi<4;++bi) r1v[bi]=ald(r1red+l*2048+(bs+bi)*256+tid);
    ln_reg<4>(r1v,ln1_g+l*256,ln1_b+l*256,RED);
    // ---- LATE: p2 partials ----
    waitflags(F2+(l*8+bs)*8*32,32,t+1);   // 4 b x 8 h
    float p2v[4][8];
#pragma unroll
    for(int bi=0;bi<4;++bi)
#pragma unroll
      for(int h2=0;h2<8;++h2) p2v[bi][h2]=ald(p2+(h2*8+bs+bi)*256+tid);
    float r2v[4];
    float cb=ca_bo[l*256+tid];
#pragma unroll
    for(int bi=0;bi<4;++bi){
      float s=0.f;
#pragma unroll
      for(int h2=0;h2<8;++h2) s+=p2v[bi][h2];
      r2v[bi]=r1v[bi]+s+cb;
    }
    if(cg==0){
#pragma unroll
      for(int bi=0;bi<4;++bi) ast(r2red+l*2048+(bs+bi)*256+tid,r2v[bi]);
      __syncthreads();                    // drain r2red stores
      if(tid<4) asti(FER2+(l*8+bs+tid)*32,t+1);
    }
    ln_reg<4>(r2v,ln2_g+l*256,ln2_b+l*256,RED+32);
#pragma unroll
    for(int bi=0;bi<4;++bi) X4[bi*256+tid]=r2v[bi];
    __syncthreads();
    // FFN1: 64 rows x 4 b, K-split 4
    {
      int row=tid>>2,kq=tid&3;
      float a0=0.f,a1=0.f,a2=0.f,a3=0.f;
#pragma unroll
      for(int i=0;i<16;++i){
        float4 w=F4(&W1[row*260+kq*64+4*i]);
        a0+=D4(w,F4(&X4[0*256+kq*64+4*i]));a1+=D4(w,F4(&X4[1*256+kq*64+4*i]));
        a2+=D4(w,F4(&X4[2*256+kq*64+4*i]));a3+=D4(w,F4(&X4[3*256+kq*64+4*i]));
      }
      a0+=__shfl_down(a0,2,64);a0+=__shfl_down(a0,1,64);
      a1+=__shfl_down(a1,2,64);a1+=__shfl_down(a1,1,64);
      a2+=__shfl_down(a2,2,64);a2+=__shfl_down(a2,1,64);
      a3+=__shfl_down(a3,2,64);a3+=__shfl_down(a3,1,64);
      if(kq==0){
        float b1v=ffn_b1[l*1024+cg*64+row];
        HH[0*68+row]=fmaxf(a0+b1v,0.f);HH[1*68+row]=fmaxf(a1+b1v,0.f);
        HH[2*68+row]=fmaxf(a2+b1v,0.f);HH[3*68+row]=fmaxf(a3+b1v,0.f);
      }
    }
    __syncthreads();
    // FFN2 partial over this 64-wide k-slice, all 256 out cols
    {
      int chunk=tid&63,bi=tid>>6;
      float ax=0.f,ay=0.f,az=0.f,aw=0.f;
      for(int k=0;k<64;++k){
        float4 w=F4(&W2T[k*260+4*chunk]);
        float hv=HH[bi*68+k];
        ax+=w.x*hv;ay+=w.y*hv;az+=w.z*hv;aw+=w.w*hv;
      }
      float* dst=p3+(size_t)l*32768+(size_t)(cg*8+bs+bi)*256+4*chunk;
      ast(dst+0,ax);ast(dst+1,ay);ast(dst+2,az);ast(dst+3,aw);
    }
    __syncthreads();
    if(tid<4) asti(F3+((l*8+bs+tid)*16+cg)*32,t+1);
  }
}

// ========================= HEAD: per-b full head ===========================
DEV void role_head(float* LDS,int b,
    const float* __restrict__ op_w1,const float* __restrict__ op_b1,
    const float* __restrict__ bn_g,const float* __restrict__ bn_b,
    const float* __restrict__ op_w2,const float* __restrict__ op_b2,
    const float* __restrict__ emb_w,
    const float* __restrict__ ln2_g,const float* __restrict__ ln2_b,
    const float* __restrict__ ln3_g,const float* __restrict__ ln3_b,
    const float* __restrict__ ffn_b2,
    const int* F3,int* FX0,const int* FER2,
    const float* r2red,const float* p3,float* xrow,float* outp){
  const int tid=threadIdx.x;
  float* X  =LDS;           // 256
  float* Y  =LDS+256;       // 256
  float* LG =LDS+512;       // 128
  float* RED=LDS+768;       // 64

  for(int t=0;t<64;++t){
    // ---- EARLY: r2red(l1) + LN2 while S3(l1) does its FFN ----
    waitflags(FER2+(8+b)*32,1,t+1);
    float t0[1]={ald(r2red+2048+b*256+tid)};
    ln_reg<1>(t0,ln2_g+256,ln2_b+256,RED);
    // ---- LATE: p3(l1) partials ----
    waitflags(F3+(8+b)*16*32,16,t+1);
    float p3v[16];
#pragma unroll
    for(int cg=0;cg<16;++cg) p3v[cg]=ald(p3+32768+(cg*8+b)*256+tid);
    float r3=t0[0]+ffn_b2[256+tid];
#pragma unroll
    for(int cg=0;cg<16;++cg) r3+=p3v[cg];
    float t1[1]={r3};
    ln_reg<1>(t1,ln3_g+256,ln3_b+256,RED+8);
    X[tid]=t1[0];
    __syncthreads();
    // y = X @ op_w1.T + b1, bn affine + relu.  K-split 16.
    {
      int g=tid&15,cc=tid>>4;
      for(int it=0;it<16;++it){
        int c2=it*16+cc;
        const float4* w4=(const float4*)(op_w1+(size_t)c2*256+g*16);
        const float4* x4=(const float4*)(X+g*16);
        float a=0.f;
#pragma unroll
        for(int i=0;i<4;++i) a+=D4(w4[i],x4[i]);
        a+=__shfl_down(a,8,64);a+=__shfl_down(a,4,64);
        a+=__shfl_down(a,2,64);a+=__shfl_down(a,1,64);
        if(g==0){
          float y=a+op_b1[c2];
          Y[c2]=fmaxf(y*BNS*bn_g[c2]+bn_b[c2],0.f);
        }
      }
    }
    __syncthreads();
    // logits = Y @ op_w2.T + b2 (128 cols), write out. K-split 16.
    {
      int g=tid&15,cc=tid>>4;
      for(int it=0;it<8;++it){
        int c2=it*16+cc;
        const float4* w4=(const float4*)(op_w2+(size_t)c2*256+g*16);
        const float4* y4=(const float4*)(Y+g*16);
        float a=0.f;
#pragma unroll
        for(int i=0;i<4;++i) a+=D4(w4[i],y4[i]);
        a+=__shfl_down(a,8,64);a+=__shfl_down(a,4,64);
        a+=__shfl_down(a,2,64);a+=__shfl_down(a,1,64);
        if(g==0){
          float v=a+op_b2[c2];
          LG[c2]=v;
          outp[((size_t)b*64+t)*128+c2]=v;
        }
      }
    }
    __syncthreads();
    // xrow[b][c] = LG . emb_w[c,:]  (K=128, K-split 8)
    if(t<63){
      int g=tid&7,cc=tid>>3;
      for(int it=0;it<8;++it){
        int c2=it*32+cc;
        const float4* w4=(const float4*)(emb_w+(size_t)c2*128+g*16);
        const float4* l4=(const float4*)(LG+g*16);
        float a=0.f;
#pragma unroll
        for(int i=0;i<4;++i) a+=D4(w4[i],l4[i]);
        a+=__shfl_down(a,4,64);a+=__shfl_down(a,2,64);a+=__shfl_down(a,1,64);
        if(g==0) ast(xrow+b*256+c2,a);
      }
    }
    __syncthreads();
    if(tid==0) asti(FX0+b*32,t+1);
  }
}

// ---------------------------------------------------------------------------

__global__ void __launch_bounds__(256,1) k_decode(
    const float* enc,const float* emb_w,const float* emb_b,
    const float* sa_wqkv,const float* sa_bqkv,const float* sa_wo,const float* sa_bo,
    const float* ca_wqkv,const float* ca_bqkv,const float* ca_wo,const float* ca_bo,
    const float* ln1_g,const float* ln1_b,const float* ln2_g,const float* ln2_b,
    const float* ffn_w1,const float* ffn_b1,const float* ffn_w2,const float* ffn_b2,
    const float* ln3_g,const float* ln3_b,
    const float* op_w1,const float* op_b1,const float* bn_g,const float* bn_b,
    const float* op_w2,const float* op_b2,
    int* FX0,int* FER1,int* FER2,int* FER3,int* F1,int* F2,int* F3,
    float* xrow,float* kc,float* vc,float* r1red,float* r2red,float* r3red,
    float* p1,float* p2,float* p3,float* outp){
  __shared__ __align__(16) float LDS[DYNF];
  const int blk=blockIdx.x;
  if(blk<16){
    role_s1<4,0>(LDS,blk>>1,(blk&1)*4,sa_wqkv,sa_bqkv,sa_wo,ln2_g,ln2_b,ln3_g,ln3_b,
                 ffn_b2,emb_b,F1,F3,FX0,FER2,FER3,kc,vc,r2red,r3red,p3,p1,xrow);
  }else if(blk<48){
    int r=blk-16;
    role_s1<2,1>(LDS,r>>2,(r&3)*2,sa_wqkv,sa_bqkv,sa_wo,ln2_g,ln2_b,ln3_g,ln3_b,
                 ffn_b2,emb_b,F1,F3,FX0,FER2,FER3,kc,vc,r2red,r3red,p3,p1,xrow);
  }else if(blk<176){
    role_s2(LDS,blk-48,enc,ca_wqkv,ca_bqkv,ca_wo,ln1_g,ln1_b,ln3_g,ln3_b,sa_bo,emb_b,
            F1,F2,FX0,FER3,FER1,r3red,r1red,p1,p2,xrow);
  }else if(blk<240){
    role_s3(LDS,blk-176,ffn_w1,ffn_b1,ffn_w2,ln1_g,ln1_b,ln2_g,ln2_b,ca_bo,
            F2,F3,FER1,FER2,r1red,r2red,p2,p3);
  }else{
    role_head(LDS,blk-240,op_w1,op_b1,bn_g,bn_b,op_w2,op_b2,emb_w,
              ln2_g,ln2_b,ln3_g,ln3_b,ffn_b2,F3,FX0,FER2,r2red,p3,xrow,outp);
  }
}

// ---------------------------------------------------------------------------

extern "C" void kernel_launch(void* const* d_in, const int* in_sizes, int n_in,
                              void* d_out, int out_size, void* d_ws, size_t ws_size,
                              hipStream_t stream) {
  (void)in_sizes;(void)n_in;(void)out_size;(void)ws_size;
  const float* enc     =(const float*)d_in[0];
  const float* emb_w   =(const float*)d_in[1];
  const float* emb_b   =(const float*)d_in[2];
  const float* sa_wqkv =(const float*)d_in[3];
  const float* sa_bqkv =(const float*)d_in[4];
  const float* sa_wo   =(const float*)d_in[5];
  const float* sa_bo   =(const float*)d_in[6];
  const float* ca_wqkv =(const float*)d_in[7];
  const float* ca_bqkv =(const float*)d_in[8];
  const float* ca_wo   =(const float*)d_in[9];
  const float* ca_bo   =(const float*)d_in[10];
  const float* ln1_g   =(const float*)d_in[11];
  const float* ln1_b   =(const float*)d_in[12];
  const float* ln2_g   =(const float*)d_in[13];
  const float* ln2_b   =(const float*)d_in[14];
  const float* ffn_w1  =(const float*)d_in[15];
  const float* ffn_b1  =(const float*)d_in[16];
  const float* ffn_w2  =(const float*)d_in[17];
  const float* ffn_b2  =(const float*)d_in[18];
  const float* ln3_g   =(const float*)d_in[19];
  const float* ln3_b   =(const float*)d_in[20];
  const float* op_w1   =(const float*)d_in[21];
  const float* op_b1   =(const float*)d_in[22];
  const float* bn_g    =(const float*)d_in[23];
  const float* bn_b    =(const float*)d_in[24];
  const float* op_w2   =(const float*)d_in[25];
  const float* op_b2   =(const float*)d_in[26];

  float* out=(float*)d_out;

  // Flags: one per 128B line (stride 32 ints).
  int* I=(int*)d_ws;
  int* FX0 =I;               // 8 slots      [0,256)
  int* FER1=I+256;           // 16 slots     [256,768)
  int* FER2=I+768;           // 16 slots     [768,1280)
  int* FER3=I+1280;          // 8 slots      [1280,1536)
  int* F1  =I+1536;          // 128 slots    [1536,5632)
  int* F2  =I+5632;          // 128 slots    [5632,9728)
  int* F3  =I+9728;          // 256 slots    [9728,17920)
  hipMemsetAsync(d_ws,0,17920*4+2048*4,stream);   // flags + xrow

  float* F=(float*)d_ws+17920;
  float* xrow =F;               // 8 x 256
  float* kc   =xrow+2048;       // 2 x 8 x 8 x 64 x 32
  float* vc   =kc+262144;
  float* r1red=vc+262144;       // 2 x 8 x 256
  float* r2red=r1red+4096;      // 2 x 8 x 256
  float* r3red=r2red+4096;      // 8 x 256
  float* p1   =r3red+2048;      // 8h x 8b x 256
  float* p2   =p1+16384;        // 8h x 8b x 256
  float* p3   =p2+16384;        // 2 x 16 x 8 x 256

  k_decode<<<248,256,0,stream>>>(
      enc,emb_w,emb_b,sa_wqkv,sa_bqkv,sa_wo,sa_bo,
      ca_wqkv,ca_bqkv,ca_wo,ca_bo,ln1_g,ln1_b,ln2_g,ln2_b,
      ffn_w1,ffn_b1,ffn_w2,ffn_b2,ln3_g,ln3_b,
      op_w1,op_b1,bn_g,bn_b,op_w2,op_b2,
      FX0,FER1,FER2,FER3,F1,F2,F3,
      xrow,kc,vc,r1red,r2red,r3red,p1,p2,p3,out);
}